// Round 2
// baseline (577.455 us; speedup 1.0000x reference)
//
#include <hip/hip_runtime.h>
#include <hip/hip_bf16.h>

// ---------------------------------------------------------------------------
// InfiniAttention on MI355X — round 2 (still unbenched; audit + m97 staging).
//   1. hs f32 -> bf16
//   2. Wq,Wk -> WqkT bf16 [4096][2048]; Wo -> WoT [2048][2048]; M -> MT
//   3. rope tables cos/sin [S][64]
//   4. fused GEMM: [q|k] = hs @ [Wq|Wk] + [bq|bk]  (global_load_lds staging)
//   5. rope/elu: qr,kr,sq,sk,v (bf16)
//   6. transpose v->vT, sk->skT  ([hd][s])
//   7. flash attention (causal) -> attn f32
//   8. mem path + sigmoid-gate combine -> comb bf16
//   9. GEMM: comb @ Wo -> d_out[0:4M)
//  10. M_new -> d_out[4M:+262144) ; 11. z_new -> d_out[+2048)
// ---------------------------------------------------------------------------

#define S_LEN 2048
#define HID 2048
#define NH 16
#define HD 128
#define SCALE_QK 0.088388347648318447f

typedef __attribute__((ext_vector_type(8))) short bf16x8;
typedef __attribute__((ext_vector_type(4))) float f32x4;

__device__ __forceinline__ short f2bf(float f) {
  __hip_bfloat16 h = __float2bfloat16(f);
  return __builtin_bit_cast(short, h);
}
__device__ __forceinline__ float bf2f(short s) {
  unsigned int u = ((unsigned int)(unsigned short)s) << 16;
  return __builtin_bit_cast(float, u);
}
// async global->LDS, 16B per lane; LDS dest = wave-uniform base + lane*16
__device__ __forceinline__ void gload16(const void* g, void* l) {
  __builtin_amdgcn_global_load_lds(
      (const __attribute__((address_space(1))) void*)g,
      (__attribute__((address_space(3))) void*)l, 16, 0, 0);
}

// --------------------------- elementwise convert ---------------------------
__global__ __launch_bounds__(256) void f32_to_bf16_kernel(
    const float* __restrict__ in, short* __restrict__ out) {
  size_t i = (size_t)(blockIdx.x * 256 + threadIdx.x) * 8;
  float4 a = *reinterpret_cast<const float4*>(in + i);
  float4 b = *reinterpret_cast<const float4*>(in + i + 4);
  alignas(16) short t[8] = {f2bf(a.x), f2bf(a.y), f2bf(a.z), f2bf(a.w),
                            f2bf(b.x), f2bf(b.y), f2bf(b.z), f2bf(b.w)};
  *reinterpret_cast<int4*>(out + i) = *reinterpret_cast<int4*>(t);
}

// --------------------------- transposes ------------------------------------
// in f32 [b][R][C] -> out bf16 [b][C][R]
__global__ __launch_bounds__(256) void transpose_f2b_kernel(
    const float* __restrict__ in, short* __restrict__ out, int R, int C) {
  __shared__ float t[32][33];
  size_t bo = (size_t)blockIdx.z * R * C;
  int r0 = blockIdx.y * 32, c0 = blockIdx.x * 32;
  int tx = threadIdx.x & 31, ty = threadIdx.x >> 5;
#pragma unroll
  for (int i = 0; i < 4; ++i)
    t[ty + i * 8][tx] = in[bo + (size_t)(r0 + ty + i * 8) * C + c0 + tx];
  __syncthreads();
#pragma unroll
  for (int i = 0; i < 4; ++i)
    out[bo + (size_t)(c0 + ty + i * 8) * R + r0 + tx] = f2bf(t[tx][ty + i * 8]);
}

// in bf16 [R][C] -> out bf16 [C][R]
__global__ __launch_bounds__(256) void transpose_b2b_kernel(
    const short* __restrict__ in, short* __restrict__ out, int R, int C) {
  __shared__ short t[32][33];
  int r0 = blockIdx.y * 32, c0 = blockIdx.x * 32;
  int tx = threadIdx.x & 31, ty = threadIdx.x >> 5;
#pragma unroll
  for (int i = 0; i < 4; ++i)
    t[ty + i * 8][tx] = in[(size_t)(r0 + ty + i * 8) * C + c0 + tx];
  __syncthreads();
#pragma unroll
  for (int i = 0; i < 4; ++i)
    out[(size_t)(c0 + ty + i * 8) * R + r0 + tx] = t[tx][ty + i * 8];
}

// --------------------------- rope tables -----------------------------------
__global__ __launch_bounds__(256) void tables_kernel(
    const int* __restrict__ pos_ids, float* __restrict__ cost,
    float* __restrict__ sint) {
  int idx = blockIdx.x * 256 + threadIdx.x;  // < 2048*64
  int s = idx >> 6, j = idx & 63;
  float pos = (float)pos_ids[s];
  float inv = powf(10000.0f, -((float)j) / 64.0f);
  float a = pos * inv;
  cost[idx] = cosf(a);
  sint[idx] = sinf(a);
}

// --------------------------- GEMM (m97 structure, dual output) --------------
// C[M][4096-or-2048] = A[M][2048] @ B (+bias), BT[N][K] stacked rows.
// cols < 2048 -> C0/bias0 ; cols >= 2048 -> C1/bias1 (block-uniform).
// 128x128 tile, BK=64, 4 waves (2x2 of 64x64), global_load_lds staging.
__global__ __launch_bounds__(256) void gemm_bt_dual_kernel(
    const short* __restrict__ A, const short* __restrict__ BT,
    const float* __restrict__ bias0, const float* __restrict__ bias1,
    float* __restrict__ C0, float* __restrict__ C1) {
  __shared__ short As[128 * 64];
  __shared__ short Bs[128 * 64];
  const int K = 2048;
  const int tid = threadIdx.x;
  const int wave = tid >> 6, lane = tid & 63;
  const int g = lane >> 4, l15 = lane & 15;
  const int wm = (wave >> 1) * 64, wn = (wave & 1) * 64;
  const int row0 = blockIdx.x * 128;
  const int colg0 = blockIdx.y * 128;  // global col in stacked-BT space

  // staging geometry: wave covers rows [wave*32, wave*32+32), 4 chunks of 8 rows
  const int ld_r = wave * 32 + (lane >> 3);  // +i*8
  const int ld_c = (lane & 7) * 8;
  const short* Ag = A + (size_t)(row0 + ld_r) * K + ld_c;
  const short* Bg = BT + (size_t)(colg0 + ld_r) * K + ld_c;
  short* Al = As + wave * 2048;  // +i*512 ; byte base + lane*16 is implicit
  short* Bl = Bs + wave * 2048;

  f32x4 acc[4][4] = {};
  for (int kt = 0; kt < K; kt += 64) {
    __syncthreads();  // all waves done reading previous tile
#pragma unroll
    for (int i = 0; i < 4; ++i) {
      gload16(Ag + kt + (size_t)i * 8 * K, Al + i * 512);
      gload16(Bg + kt + (size_t)i * 8 * K, Bl + i * 512);
    }
    __syncthreads();  // compiler emits vmcnt(0) drain before barrier
#pragma unroll
    for (int ks = 0; ks < 2; ++ks) {
      bf16x8 a[4], b[4];
#pragma unroll
      for (int m = 0; m < 4; ++m)
        a[m] = *reinterpret_cast<bf16x8*>(
            reinterpret_cast<char*>(As) + (wm + m * 16 + l15) * 128 +
            (ks * 32 + g * 8) * 2);
#pragma unroll
      for (int n = 0; n < 4; ++n)
        b[n] = *reinterpret_cast<bf16x8*>(
            reinterpret_cast<char*>(Bs) + (wn + n * 16 + l15) * 128 +
            (ks * 32 + g * 8) * 2);
#pragma unroll
      for (int m = 0; m < 4; ++m)
#pragma unroll
        for (int n = 0; n < 4; ++n)
          acc[m][n] = __builtin_amdgcn_mfma_f32_16x16x32_bf16(a[m], b[n],
                                                              acc[m][n], 0, 0, 0);
    }
  }

  float* C = (colg0 < 2048) ? C0 : C1;
  const float* bias = (colg0 < 2048) ? bias0 : bias1;
  const int col0 = (colg0 < 2048) ? colg0 : colg0 - 2048;
#pragma unroll
  for (int m = 0; m < 4; ++m)
#pragma unroll
    for (int n = 0; n < 4; ++n) {
      int row = row0 + wm + m * 16 + g * 4;
      int col = col0 + wn + n * 16 + l15;
      float bv = bias ? bias[col] : 0.0f;
#pragma unroll
      for (int r = 0; r < 4; ++r)
        C[(size_t)(row + r) * 2048 + col] = acc[m][n][r] + bv;
    }
}

// --------------------------- rope / elu ------------------------------------
__global__ __launch_bounds__(256) void rope_kernel(
    const float* __restrict__ qf, const float* __restrict__ kf,
    const float* __restrict__ cost, const float* __restrict__ sint,
    short* __restrict__ qr, short* __restrict__ kr, short* __restrict__ sq,
    short* __restrict__ sk, short* __restrict__ v) {
  int s = blockIdx.x;
  int hd = threadIdx.x * 8;
  int d = hd & 127;
  bool lo = d < 64;
  size_t base = (size_t)s * HID + hd;
  size_t pb = lo ? base + 64 : base - 64;
  int tb = s * 64 + (hd & 63);
  alignas(16) short oqr[8], okr[8], osq[8], osk[8], ov[8];
#pragma unroll
  for (int j = 0; j < 8; ++j) {
    float c = cost[tb + j], sn = sint[tb + j];
    float q = qf[base + j], qp = qf[pb + j];
    float k = kf[base + j], kp = kf[pb + j];
    float rq = lo ? -qp : qp;
    float rk = lo ? -kp : kp;
    float qrv = q * c + rq * sn;
    float krv = k * c + rk * sn;
    oqr[j] = f2bf(qrv);
    okr[j] = f2bf(krv);
    osq[j] = f2bf(qrv > 0.0f ? qrv + 1.0f : expf(qrv));
    osk[j] = f2bf(krv > 0.0f ? krv + 1.0f : expf(krv));
    ov[j] = f2bf(q);
  }
  *reinterpret_cast<int4*>(qr + base) = *reinterpret_cast<int4*>(oqr);
  *reinterpret_cast<int4*>(kr + base) = *reinterpret_cast<int4*>(okr);
  *reinterpret_cast<int4*>(sq + base) = *reinterpret_cast<int4*>(osq);
  *reinterpret_cast<int4*>(sk + base) = *reinterpret_cast<int4*>(osk);
  *reinterpret_cast<int4*>(v + base) = *reinterpret_cast<int4*>(ov);
}

// --------------------------- flash attention -------------------------------
// block = (q-tile of 128 rows, head). 4 waves x 32 q-rows. K/V tiles of 128.
__global__ __launch_bounds__(256) void attn_kernel(
    const short* __restrict__ qr, const short* __restrict__ kr,
    const short* __restrict__ vT, float* __restrict__ attn_out) {
  __shared__ short kr_s[128 * 128];
  __shared__ short vT_s[128 * 128];
  __shared__ short p_s[4][32 * 128];
  const int tid = threadIdx.x;
  const int wave = tid >> 6, lane = tid & 63;
  const int g = lane >> 4, l15 = lane & 15;
  const int h = blockIdx.y;
  const int qt = blockIdx.x;
  const int q0 = qt * 128;

  bf16x8 qf[2][4];
#pragma unroll
  for (int m = 0; m < 2; ++m)
#pragma unroll
    for (int ks = 0; ks < 4; ++ks) {
      int row = q0 + wave * 32 + m * 16 + l15;
      int d = ks * 32 + g * 8;
      qf[m][ks] =
          *reinterpret_cast<const bf16x8*>(qr + (size_t)row * HID + h * HD + d);
    }

  f32x4 o[2][8] = {};
  float m_run[2][4], l_run[2][4];
#pragma unroll
  for (int m = 0; m < 2; ++m)
#pragma unroll
    for (int r = 0; r < 4; ++r) {
      m_run[m][r] = -3.0e38f;
      l_run[m][r] = 0.0f;
    }

  for (int kt = 0; kt <= qt; ++kt) {
    const int t0 = kt * 128;
    __syncthreads();
#pragma unroll
    for (int i = 0; i < 8; ++i) {
      int c = tid + 256 * i;
      int r = c >> 4, kc = c & 15;
      int off = (r * 256 + kc * 16) ^ ((r & 7) << 4);
      *reinterpret_cast<int4*>(reinterpret_cast<char*>(kr_s) + off) =
          *reinterpret_cast<const int4*>(kr + (size_t)(t0 + r) * HID + h * HD +
                                         kc * 8);
      *reinterpret_cast<int4*>(reinterpret_cast<char*>(vT_s) + off) =
          *reinterpret_cast<const int4*>(vT + (size_t)(h * HD + r) * S_LEN + t0 +
                                         kc * 8);
    }
    __syncthreads();

    f32x4 sfr[2][8] = {};
#pragma unroll
    for (int n = 0; n < 8; ++n) {
#pragma unroll
      for (int ks = 0; ks < 4; ++ks) {
        int rr = n * 16 + l15;
        int off = (rr * 256 + (ks * 32 + g * 8) * 2) ^ ((rr & 7) << 4);
        bf16x8 b =
            *reinterpret_cast<bf16x8*>(reinterpret_cast<char*>(kr_s) + off);
#pragma unroll
        for (int m = 0; m < 2; ++m)
          sfr[m][n] = __builtin_amdgcn_mfma_f32_16x16x32_bf16(qf[m][ks], b,
                                                              sfr[m][n], 0, 0, 0);
      }
    }

    // online softmax (rows owned per 16-lane group)
#pragma unroll
    for (int m = 0; m < 2; ++m) {
#pragma unroll
      for (int r = 0; r < 4; ++r) {
        const int srow = q0 + wave * 32 + m * 16 + g * 4 + r;
        float mx = m_run[m][r];
#pragma unroll
        for (int n = 0; n < 8; ++n) {
          int t = t0 + n * 16 + l15;
          float val = sfr[m][n][r] * SCALE_QK;
          val = (t <= srow) ? val : -3.0e38f;
          sfr[m][n][r] = val;
          mx = fmaxf(mx, val);
        }
        mx = fmaxf(mx, __shfl_xor(mx, 1));
        mx = fmaxf(mx, __shfl_xor(mx, 2));
        mx = fmaxf(mx, __shfl_xor(mx, 4));
        mx = fmaxf(mx, __shfl_xor(mx, 8));
        float sum = 0.0f;
#pragma unroll
        for (int n = 0; n < 8; ++n) {
          float p = expf(sfr[m][n][r] - mx);
          sfr[m][n][r] = p;
          sum += p;
        }
        sum += __shfl_xor(sum, 1);
        sum += __shfl_xor(sum, 2);
        sum += __shfl_xor(sum, 4);
        sum += __shfl_xor(sum, 8);
        float f = expf(m_run[m][r] - mx);
        l_run[m][r] = l_run[m][r] * f + sum;
        m_run[m][r] = mx;
#pragma unroll
        for (int n = 0; n < 8; ++n) o[m][n][r] *= f;
      }
    }

    // P -> bf16 -> wave-private swizzled LDS
    char* pw = reinterpret_cast<char*>(p_s[wave]);
#pragma unroll
    for (int m = 0; m < 2; ++m)
#pragma unroll
      for (int n = 0; n < 8; ++n)
#pragma unroll
        for (int r = 0; r < 4; ++r) {
          int rl = m * 16 + g * 4 + r;
          int off = (rl * 256 + (n * 16 + l15) * 2) ^ ((rl & 7) << 4);
          *reinterpret_cast<short*>(pw + off) = f2bf(sfr[m][n][r]);
        }

    // PV
#pragma unroll
    for (int ks = 0; ks < 4; ++ks) {
      bf16x8 pa[2];
#pragma unroll
      for (int m = 0; m < 2; ++m) {
        int rl = m * 16 + l15;
        int off = (rl * 256 + (ks * 32 + g * 8) * 2) ^ ((rl & 7) << 4);
        pa[m] = *reinterpret_cast<bf16x8*>(pw + off);
      }
#pragma unroll
      for (int n = 0; n < 8; ++n) {
        int rr = n * 16 + l15;
        int off = (rr * 256 + (ks * 32 + g * 8) * 2) ^ ((rr & 7) << 4);
        bf16x8 vb =
            *reinterpret_cast<bf16x8*>(reinterpret_cast<char*>(vT_s) + off);
#pragma unroll
        for (int m = 0; m < 2; ++m)
          o[m][n] = __builtin_amdgcn_mfma_f32_16x16x32_bf16(pa[m], vb, o[m][n],
                                                            0, 0, 0);
      }
    }
  }

#pragma unroll
  for (int m = 0; m < 2; ++m)
#pragma unroll
    for (int n = 0; n < 8; ++n)
#pragma unroll
      for (int r = 0; r < 4; ++r) {
        int row = q0 + wave * 32 + m * 16 + g * 4 + r;
        int col = n * 16 + l15;
        attn_out[(size_t)row * HID + h * HD + col] = o[m][n][r] / l_run[m][r];
      }
}

// --------------------------- memory path + gate combine ---------------------
__global__ __launch_bounds__(256) void mem_combine_kernel(
    const short* __restrict__ sq, const short* __restrict__ MT,
    const float* __restrict__ z, const float* __restrict__ attn,
    const float* __restrict__ beta, short* __restrict__ combined) {
  __shared__ short mt_s[128 * 128];
  const int tid = threadIdx.x;
  const int wave = tid >> 6, lane = tid & 63;
  const int g = lane >> 4, l15 = lane & 15;
  const int h = blockIdx.y;
  const int s0 = blockIdx.x * 128;
#pragma unroll
  for (int i = 0; i < 8; ++i) {
    int c = tid + 256 * i;
    int r = c >> 4, kc = c & 15;
    int off = (r * 256 + kc * 16) ^ ((r & 7) << 4);
    *reinterpret_cast<int4*>(reinterpret_cast<char*>(mt_s) + off) =
        *reinterpret_cast<const int4*>(MT + (size_t)h * 16384 + r * 128 + kc * 8);
  }
  __syncthreads();

  f32x4 acc[2][8] = {};
#pragma unroll
  for (int ks = 0; ks < 4; ++ks) {
    bf16x8 a[2];
#pragma unroll
    for (int m = 0; m < 2; ++m) {
      int row = s0 + wave * 32 + m * 16 + l15;
      a[m] = *reinterpret_cast<const bf16x8*>(sq + (size_t)row * HID + h * HD +
                                              ks * 32 + g * 8);
    }
#pragma unroll
    for (int n = 0; n < 8; ++n) {
      int rr = n * 16 + l15;
      int off = (rr * 256 + (ks * 32 + g * 8) * 2) ^ ((rr & 7) << 4);
      bf16x8 b = *reinterpret_cast<bf16x8*>(reinterpret_cast<char*>(mt_s) + off);
#pragma unroll
      for (int m = 0; m < 2; ++m)
        acc[m][n] =
            __builtin_amdgcn_mfma_f32_16x16x32_bf16(a[m], b, acc[m][n], 0, 0, 0);
    }
  }

  float den[2][4];
#pragma unroll
  for (int m = 0; m < 2; ++m)
#pragma unroll
    for (int r = 0; r < 4; ++r) {
      int row = s0 + wave * 32 + m * 16 + g * 4 + r;
      bf16x8 sv = *reinterpret_cast<const bf16x8*>(sq + (size_t)row * HID +
                                                   h * HD + l15 * 8);
      float part = 0.0f;
#pragma unroll
      for (int j = 0; j < 8; ++j) part += bf2f(sv[j]) * z[h * HD + l15 * 8 + j];
      part += __shfl_xor(part, 1);
      part += __shfl_xor(part, 2);
      part += __shfl_xor(part, 4);
      part += __shfl_xor(part, 8);
      den[m][r] = part + 1e-8f;
    }
  float gv = 1.0f / (1.0f + expf(-beta[0]));
#pragma unroll
  for (int m = 0; m < 2; ++m)
#pragma unroll
    for (int n = 0; n < 8; ++n)
#pragma unroll
      for (int r = 0; r < 4; ++r) {
        int row = s0 + wave * 32 + m * 16 + g * 4 + r;
        int col = n * 16 + l15;
        float mem = acc[m][n][r] / den[m][r];
        float at = attn[(size_t)row * HID + h * HD + col];
        combined[(size_t)row * HID + h * HD + col] =
            f2bf(gv * mem + (1.0f - gv) * at);
      }
}

// --------------------------- M_new -----------------------------------------
__global__ __launch_bounds__(256) void mnew_kernel(
    const short* __restrict__ skT, const short* __restrict__ vT,
    const float* __restrict__ Mold, float* __restrict__ Mout) {
  const int h = blockIdx.x;
  const int tid = threadIdx.x;
  const int wave = tid >> 6, lane = tid & 63;
  const int g = lane >> 4, l15 = lane & 15;
  f32x4 acc[2][8] = {};
  for (int ks = 0; ks < 64; ++ks) {
    bf16x8 a[2];
#pragma unroll
    for (int m = 0; m < 2; ++m) {
      int dd = wave * 32 + m * 16 + l15;
      a[m] = *reinterpret_cast<const bf16x8*>(skT + (size_t)(h * HD + dd) * S_LEN +
                                              ks * 32 + g * 8);
    }
#pragma unroll
    for (int n = 0; n < 8; ++n) {
      int e = n * 16 + l15;
      bf16x8 b = *reinterpret_cast<const bf16x8*>(
          vT + (size_t)(h * HD + e) * S_LEN + ks * 32 + g * 8);
#pragma unroll
      for (int m = 0; m < 2; ++m)
        acc[m][n] =
            __builtin_amdgcn_mfma_f32_16x16x32_bf16(a[m], b, acc[m][n], 0, 0, 0);
    }
  }
#pragma unroll
  for (int m = 0; m < 2; ++m)
#pragma unroll
    for (int n = 0; n < 8; ++n)
#pragma unroll
      for (int r = 0; r < 4; ++r) {
        int dd = wave * 32 + m * 16 + g * 4 + r;
        int e = n * 16 + l15;
        size_t idx = (size_t)h * 16384 + (size_t)dd * 128 + e;
        Mout[idx] = Mold[idx] + acc[m][n][r];
      }
}

// --------------------------- z_new -----------------------------------------
__global__ __launch_bounds__(256) void znew_kernel(const short* __restrict__ skT,
                                                   const float* __restrict__ z,
                                                   float* __restrict__ out) {
  int row = blockIdx.x;  // hd in [0,2048)
  int tid = threadIdx.x;
  bf16x8 vv = *reinterpret_cast<const bf16x8*>(skT + (size_t)row * S_LEN + tid * 8);
  float s = 0.0f;
#pragma unroll
  for (int j = 0; j < 8; ++j) s += bf2f(vv[j]);
#pragma unroll
  for (int off = 1; off < 64; off <<= 1) s += __shfl_xor(s, off);
  __shared__ float wsum[4];
  if ((tid & 63) == 0) wsum[tid >> 6] = s;
  __syncthreads();
  if (tid == 0) out[row] = z[row] + wsum[0] + wsum[1] + wsum[2] + wsum[3];
}

// ---------------------------------------------------------------------------
extern "C" void kernel_launch(void* const* d_in, const int* in_sizes, int n_in,
                              void* d_out, int out_size, void* d_ws,
                              size_t ws_size, hipStream_t stream) {
  const float* hs = (const float*)d_in[0];
  // d_in[1] attention_mask: deterministic causal -1e9, handled analytically
  const int* pos = (const int*)d_in[2];
  const float* Wq = (const float*)d_in[3];
  const float* bq = (const float*)d_in[4];
  const float* Wk = (const float*)d_in[5];
  const float* bk = (const float*)d_in[6];
  const float* Wo = (const float*)d_in[7];
  const float* beta = (const float*)d_in[8];
  const float* Mm = (const float*)d_in[9];
  const float* z = (const float*)d_in[10];
  float* out = (float*)d_out;

  char* ws = (char*)d_ws;
  const size_t MB = 1u << 20;
  float* q_f32 = (float*)(ws + 0);         // 16MB ; -> attn after rope
  float* k_f32 = (float*)(ws + 16 * MB);   // 16MB ; -> comb after rope
  short* hs_b = (short*)(ws + 32 * MB);    // 8MB  ; -> sk after fused GEMM
  short* WqkT = (short*)(ws + 40 * MB);    // 16MB ; -> v/skT after fused GEMM
  short* WoT = (short*)(ws + 56 * MB);     // 8MB
  short* qr = (short*)(ws + 64 * MB);      // 8MB
  short* kr = (short*)(ws + 72 * MB);      // 8MB
  short* sq = (short*)(ws + 80 * MB);      // 8MB
  short* vT = (short*)(ws + 88 * MB);      // 8MB
  short* MT = (short*)(ws + 96 * MB);      // 512KB
  float* cost = (float*)(ws + 96 * MB + 512 * 1024);   // 512KB
  float* sint = (float*)(ws + 97 * MB);                // 512KB
  // lifetime-checked aliases:
  float* attn = q_f32;
  short* comb = (short*)k_f32;
  short* sk = hs_b;                 // hs_b dead after fused GEMM
  short* v = WqkT;                  // WqkT[0:4M shorts] dead after fused GEMM
  short* skT = WqkT + 4 * 1024 * 1024;  // WqkT[4M:8M shorts]

  f32_to_bf16_kernel<<<2048, 256, 0, stream>>>(hs, hs_b);
  transpose_f2b_kernel<<<dim3(64, 64, 1), 256, 0, stream>>>(Wq, WqkT, 2048, 2048);
  transpose_f2b_kernel<<<dim3(64, 64, 1), 256, 0, stream>>>(
      Wk, WqkT + 4 * 1024 * 1024, 2048, 2048);
  transpose_f2b_kernel<<<dim3(64, 64, 1), 256, 0, stream>>>(Wo, WoT, 2048, 2048);
  transpose_f2b_kernel<<<dim3(4, 4, 16), 256, 0, stream>>>(Mm, MT, 128, 128);
  tables_kernel<<<512, 256, 0, stream>>>(pos, cost, sint);

  // fused q|k projection: 512 blocks (2/CU)
  gemm_bt_dual_kernel<<<dim3(16, 32), 256, 0, stream>>>(hs_b, WqkT, bq, bk,
                                                        q_f32, k_f32);
  rope_kernel<<<2048, 256, 0, stream>>>(q_f32, k_f32, cost, sint, qr, kr, sq, sk,
                                        v);
  transpose_b2b_kernel<<<dim3(64, 64, 1), 256, 0, stream>>>(v, vT, 2048, 2048);
  transpose_b2b_kernel<<<dim3(64, 64, 1), 256, 0, stream>>>(sk, skT, 2048, 2048);

  attn_kernel<<<dim3(16, 16), 256, 0, stream>>>(qr, kr, vT, attn);
  mem_combine_kernel<<<dim3(16, 16), 256, 0, stream>>>(sq, MT, z, attn, beta,
                                                       comb);
  gemm_bt_dual_kernel<<<dim3(16, 16), 256, 0, stream>>>(comb, WoT, nullptr,
                                                        nullptr, out, out);
  mnew_kernel<<<16, 256, 0, stream>>>(skT, vT, Mm, out + 4194304);
  znew_kernel<<<2048, 256, 0, stream>>>(skT, z, out + 4194304 + 16 * 128 * 128);
}

// Round 4
// 442.917 us; speedup vs baseline: 1.3038x; 1.3038x over previous
//
#include <hip/hip_runtime.h>
#include <hip/hip_bf16.h>

// ---------------------------------------------------------------------------
// InfiniAttention on MI355X — round 4 (= round-3 kernel, never benched).
// R2 profile: attn 202us @ 6.4% occupancy (1 blk/CU x causal imbalance).
// This round: attn QBLK=64, 80KB LDS -> 2 blk/CU, balanced qt pairing, __expf;
//     mnew split-K (16 -> 128 blocks + reduce). GEMMs unchanged (unprofiled).
// ---------------------------------------------------------------------------

#define S_LEN 2048
#define HID 2048
#define NH 16
#define HD 128
#define SCALE_QK 0.088388347648318447f

typedef __attribute__((ext_vector_type(8))) short bf16x8;
typedef __attribute__((ext_vector_type(4))) float f32x4;

__device__ __forceinline__ short f2bf(float f) {
  __hip_bfloat16 h = __float2bfloat16(f);
  return __builtin_bit_cast(short, h);
}
__device__ __forceinline__ float bf2f(short s) {
  unsigned int u = ((unsigned int)(unsigned short)s) << 16;
  return __builtin_bit_cast(float, u);
}
__device__ __forceinline__ void gload16(const void* g, void* l) {
  __builtin_amdgcn_global_load_lds(
      (const __attribute__((address_space(1))) void*)g,
      (__attribute__((address_space(3))) void*)l, 16, 0, 0);
}

// --------------------------- elementwise convert ---------------------------
__global__ __launch_bounds__(256) void f32_to_bf16_kernel(
    const float* __restrict__ in, short* __restrict__ out) {
  size_t i = (size_t)(blockIdx.x * 256 + threadIdx.x) * 8;
  float4 a = *reinterpret_cast<const float4*>(in + i);
  float4 b = *reinterpret_cast<const float4*>(in + i + 4);
  alignas(16) short t[8] = {f2bf(a.x), f2bf(a.y), f2bf(a.z), f2bf(a.w),
                            f2bf(b.x), f2bf(b.y), f2bf(b.z), f2bf(b.w)};
  *reinterpret_cast<int4*>(out + i) = *reinterpret_cast<int4*>(t);
}

// --------------------------- transposes ------------------------------------
__global__ __launch_bounds__(256) void transpose_f2b_kernel(
    const float* __restrict__ in, short* __restrict__ out, int R, int C) {
  __shared__ float t[32][33];
  size_t bo = (size_t)blockIdx.z * R * C;
  int r0 = blockIdx.y * 32, c0 = blockIdx.x * 32;
  int tx = threadIdx.x & 31, ty = threadIdx.x >> 5;
#pragma unroll
  for (int i = 0; i < 4; ++i)
    t[ty + i * 8][tx] = in[bo + (size_t)(r0 + ty + i * 8) * C + c0 + tx];
  __syncthreads();
#pragma unroll
  for (int i = 0; i < 4; ++i)
    out[bo + (size_t)(c0 + ty + i * 8) * R + r0 + tx] = f2bf(t[tx][ty + i * 8]);
}

__global__ __launch_bounds__(256) void transpose_b2b_kernel(
    const short* __restrict__ in, short* __restrict__ out, int R, int C) {
  __shared__ short t[32][33];
  int r0 = blockIdx.y * 32, c0 = blockIdx.x * 32;
  int tx = threadIdx.x & 31, ty = threadIdx.x >> 5;
#pragma unroll
  for (int i = 0; i < 4; ++i)
    t[ty + i * 8][tx] = in[(size_t)(r0 + ty + i * 8) * C + c0 + tx];
  __syncthreads();
#pragma unroll
  for (int i = 0; i < 4; ++i)
    out[(size_t)(c0 + ty + i * 8) * R + r0 + tx] = t[tx][ty + i * 8];
}

// --------------------------- rope tables -----------------------------------
__global__ __launch_bounds__(256) void tables_kernel(
    const int* __restrict__ pos_ids, float* __restrict__ cost,
    float* __restrict__ sint) {
  int idx = blockIdx.x * 256 + threadIdx.x;
  int s = idx >> 6, j = idx & 63;
  float pos = (float)pos_ids[s];
  float inv = powf(10000.0f, -((float)j) / 64.0f);
  float a = pos * inv;
  cost[idx] = cosf(a);
  sint[idx] = sinf(a);
}

// --------------------------- GEMM (m97 structure, dual output) --------------
__global__ __launch_bounds__(256) void gemm_bt_dual_kernel(
    const short* __restrict__ A, const short* __restrict__ BT,
    const float* __restrict__ bias0, const float* __restrict__ bias1,
    float* __restrict__ C0, float* __restrict__ C1) {
  __shared__ short As[128 * 64];
  __shared__ short Bs[128 * 64];
  const int K = 2048;
  const int tid = threadIdx.x;
  const int wave = tid >> 6, lane = tid & 63;
  const int g = lane >> 4, l15 = lane & 15;
  const int wm = (wave >> 1) * 64, wn = (wave & 1) * 64;
  const int row0 = blockIdx.x * 128;
  const int colg0 = blockIdx.y * 128;

  const int ld_r = wave * 32 + (lane >> 3);
  const int ld_c = (lane & 7) * 8;
  const short* Ag = A + (size_t)(row0 + ld_r) * K + ld_c;
  const short* Bg = BT + (size_t)(colg0 + ld_r) * K + ld_c;
  short* Al = As + wave * 2048;
  short* Bl = Bs + wave * 2048;

  f32x4 acc[4][4] = {};
  for (int kt = 0; kt < K; kt += 64) {
    __syncthreads();
#pragma unroll
    for (int i = 0; i < 4; ++i) {
      gload16(Ag + kt + (size_t)i * 8 * K, Al + i * 512);
      gload16(Bg + kt + (size_t)i * 8 * K, Bl + i * 512);
    }
    __syncthreads();
#pragma unroll
    for (int ks = 0; ks < 2; ++ks) {
      bf16x8 a[4], b[4];
#pragma unroll
      for (int m = 0; m < 4; ++m)
        a[m] = *reinterpret_cast<bf16x8*>(
            reinterpret_cast<char*>(As) + (wm + m * 16 + l15) * 128 +
            (ks * 32 + g * 8) * 2);
#pragma unroll
      for (int n = 0; n < 4; ++n)
        b[n] = *reinterpret_cast<bf16x8*>(
            reinterpret_cast<char*>(Bs) + (wn + n * 16 + l15) * 128 +
            (ks * 32 + g * 8) * 2);
#pragma unroll
      for (int m = 0; m < 4; ++m)
#pragma unroll
        for (int n = 0; n < 4; ++n)
          acc[m][n] = __builtin_amdgcn_mfma_f32_16x16x32_bf16(a[m], b[n],
                                                              acc[m][n], 0, 0, 0);
    }
  }

  float* C = (colg0 < 2048) ? C0 : C1;
  const float* bias = (colg0 < 2048) ? bias0 : bias1;
  const int col0 = (colg0 < 2048) ? colg0 : colg0 - 2048;
#pragma unroll
  for (int m = 0; m < 4; ++m)
#pragma unroll
    for (int n = 0; n < 4; ++n) {
      int row = row0 + wm + m * 16 + g * 4;
      int col = col0 + wn + n * 16 + l15;
      float bv = bias ? bias[col] : 0.0f;
#pragma unroll
      for (int r = 0; r < 4; ++r)
        C[(size_t)(row + r) * 2048 + col] = acc[m][n][r] + bv;
    }
}

// --------------------------- rope / elu ------------------------------------
__global__ __launch_bounds__(256) void rope_kernel(
    const float* __restrict__ qf, const float* __restrict__ kf,
    const float* __restrict__ cost, const float* __restrict__ sint,
    short* __restrict__ qr, short* __restrict__ kr, short* __restrict__ sq,
    short* __restrict__ sk, short* __restrict__ v) {
  int s = blockIdx.x;
  int hd = threadIdx.x * 8;
  int d = hd & 127;
  bool lo = d < 64;
  size_t base = (size_t)s * HID + hd;
  size_t pb = lo ? base + 64 : base - 64;
  int tb = s * 64 + (hd & 63);
  alignas(16) short oqr[8], okr[8], osq[8], osk[8], ov[8];
#pragma unroll
  for (int j = 0; j < 8; ++j) {
    float c = cost[tb + j], sn = sint[tb + j];
    float q = qf[base + j], qp = qf[pb + j];
    float k = kf[base + j], kp = kf[pb + j];
    float rq = lo ? -qp : qp;
    float rk = lo ? -kp : kp;
    float qrv = q * c + rq * sn;
    float krv = k * c + rk * sn;
    oqr[j] = f2bf(qrv);
    okr[j] = f2bf(krv);
    osq[j] = f2bf(qrv > 0.0f ? qrv + 1.0f : __expf(qrv));
    osk[j] = f2bf(krv > 0.0f ? krv + 1.0f : __expf(krv));
    ov[j] = f2bf(q);
  }
  *reinterpret_cast<int4*>(qr + base) = *reinterpret_cast<int4*>(oqr);
  *reinterpret_cast<int4*>(kr + base) = *reinterpret_cast<int4*>(okr);
  *reinterpret_cast<int4*>(sq + base) = *reinterpret_cast<int4*>(osq);
  *reinterpret_cast<int4*>(sk + base) = *reinterpret_cast<int4*>(osk);
  *reinterpret_cast<int4*>(v + base) = *reinterpret_cast<int4*>(ov);
}

// --------------------------- flash attention -------------------------------
// 512 blocks, QBLK=64 (4 waves x 16 q-rows), KVBLK=128, 80KB LDS (2 blk/CU).
// Balanced causal pairing: co-resident blocks (bid, bid+256) do 17 tiles total.
__global__ __launch_bounds__(256) void attn_kernel(
    const short* __restrict__ qr, const short* __restrict__ kr,
    const short* __restrict__ vT, float* __restrict__ attn_out) {
  __shared__ short kr_s[128 * 128];   // 32KB
  __shared__ short vT_s[128 * 128];   // 32KB
  __shared__ short p_s[4][16 * 128];  // 16KB
  const int tid = threadIdx.x;
  const int wave = tid >> 6, lane = tid & 63;
  const int g = lane >> 4, l15 = lane & 15;
  const int bid = blockIdx.x;
  const int h = bid & 15;
  const int u = bid >> 4;  // 0..31
  const int qt = (u < 16) ? (2 * u) : (31 - 2 * (u - 16));
  const int q0 = qt * 64;
  const int ntiles = (qt >> 1) + 1;

  bf16x8 qf[4];
#pragma unroll
  for (int ks = 0; ks < 4; ++ks) {
    int row = q0 + wave * 16 + l15;
    qf[ks] = *reinterpret_cast<const bf16x8*>(qr + (size_t)row * HID + h * HD +
                                              ks * 32 + g * 8);
  }

  f32x4 o[8] = {};
  float m_run[4], l_run[4];
#pragma unroll
  for (int r = 0; r < 4; ++r) {
    m_run[r] = -3.0e38f;
    l_run[r] = 0.0f;
  }

  for (int kt = 0; kt < ntiles; ++kt) {
    const int t0 = kt * 128;
    __syncthreads();
#pragma unroll
    for (int i = 0; i < 8; ++i) {
      int c = tid + 256 * i;
      int r = c >> 4, kc = c & 15;
      int off = (r * 256 + kc * 16) ^ ((r & 7) << 4);
      *reinterpret_cast<int4*>(reinterpret_cast<char*>(kr_s) + off) =
          *reinterpret_cast<const int4*>(kr + (size_t)(t0 + r) * HID + h * HD +
                                         kc * 8);
      *reinterpret_cast<int4*>(reinterpret_cast<char*>(vT_s) + off) =
          *reinterpret_cast<const int4*>(vT + (size_t)(h * HD + r) * S_LEN + t0 +
                                         kc * 8);
    }
    __syncthreads();

    f32x4 sfr[8] = {};
#pragma unroll
    for (int n = 0; n < 8; ++n) {
#pragma unroll
      for (int ks = 0; ks < 4; ++ks) {
        int rr = n * 16 + l15;
        int off = (rr * 256 + (ks * 32 + g * 8) * 2) ^ ((rr & 7) << 4);
        bf16x8 b =
            *reinterpret_cast<bf16x8*>(reinterpret_cast<char*>(kr_s) + off);
        sfr[n] = __builtin_amdgcn_mfma_f32_16x16x32_bf16(qf[ks], b, sfr[n], 0,
                                                         0, 0);
      }
    }

    // online softmax: each (g,r) owns a q-row; 16 l15 lanes hold its cols
#pragma unroll
    for (int r = 0; r < 4; ++r) {
      const int srow = q0 + wave * 16 + g * 4 + r;
      float mx = m_run[r];
#pragma unroll
      for (int n = 0; n < 8; ++n) {
        int t = t0 + n * 16 + l15;
        float val = sfr[n][r] * SCALE_QK;
        val = (t <= srow) ? val : -3.0e38f;
        sfr[n][r] = val;
        mx = fmaxf(mx, val);
      }
      mx = fmaxf(mx, __shfl_xor(mx, 1));
      mx = fmaxf(mx, __shfl_xor(mx, 2));
      mx = fmaxf(mx, __shfl_xor(mx, 4));
      mx = fmaxf(mx, __shfl_xor(mx, 8));
      float sum = 0.0f;
#pragma unroll
      for (int n = 0; n < 8; ++n) {
        float p = __expf(sfr[n][r] - mx);
        sfr[n][r] = p;
        sum += p;
      }
      sum += __shfl_xor(sum, 1);
      sum += __shfl_xor(sum, 2);
      sum += __shfl_xor(sum, 4);
      sum += __shfl_xor(sum, 8);
      float f = __expf(m_run[r] - mx);
      l_run[r] = l_run[r] * f + sum;
      m_run[r] = mx;
#pragma unroll
      for (int n = 0; n < 8; ++n) o[n][r] *= f;
    }

    // P -> bf16 -> wave-private swizzled LDS (16 rows x 128)
    char* pw = reinterpret_cast<char*>(p_s[wave]);
#pragma unroll
    for (int n = 0; n < 8; ++n)
#pragma unroll
      for (int r = 0; r < 4; ++r) {
        int rl = g * 4 + r;
        int off = (rl * 256 + (n * 16 + l15) * 2) ^ ((rl & 7) << 4);
        *reinterpret_cast<short*>(pw + off) = f2bf(sfr[n][r]);
      }

    // PV
#pragma unroll
    for (int ks = 0; ks < 4; ++ks) {
      int offp = (l15 * 256 + (ks * 32 + g * 8) * 2) ^ ((l15 & 7) << 4);
      bf16x8 pa = *reinterpret_cast<bf16x8*>(pw + offp);
#pragma unroll
      for (int n = 0; n < 8; ++n) {
        int rr = n * 16 + l15;
        int off = (rr * 256 + (ks * 32 + g * 8) * 2) ^ ((rr & 7) << 4);
        bf16x8 vb =
            *reinterpret_cast<bf16x8*>(reinterpret_cast<char*>(vT_s) + off);
        o[n] = __builtin_amdgcn_mfma_f32_16x16x32_bf16(pa, vb, o[n], 0, 0, 0);
      }
    }
  }

#pragma unroll
  for (int n = 0; n < 8; ++n)
#pragma unroll
    for (int r = 0; r < 4; ++r) {
      int row = q0 + wave * 16 + g * 4 + r;
      int col = n * 16 + l15;
      attn_out[(size_t)row * HID + h * HD + col] = o[n][r] / l_run[r];
    }
}

// --------------------------- memory path + gate combine ---------------------
__global__ __launch_bounds__(256) void mem_combine_kernel(
    const short* __restrict__ sq, const short* __restrict__ MT,
    const float* __restrict__ z, const float* __restrict__ attn,
    const float* __restrict__ beta, short* __restrict__ combined) {
  __shared__ short mt_s[128 * 128];
  const int tid = threadIdx.x;
  const int wave = tid >> 6, lane = tid & 63;
  const int g = lane >> 4, l15 = lane & 15;
  const int h = blockIdx.y;
  const int s0 = blockIdx.x * 128;
#pragma unroll
  for (int i = 0; i < 8; ++i) {
    int c = tid + 256 * i;
    int r = c >> 4, kc = c & 15;
    int off = (r * 256 + kc * 16) ^ ((r & 7) << 4);
    *reinterpret_cast<int4*>(reinterpret_cast<char*>(mt_s) + off) =
        *reinterpret_cast<const int4*>(MT + (size_t)h * 16384 + r * 128 + kc * 8);
  }
  __syncthreads();

  f32x4 acc[2][8] = {};
#pragma unroll
  for (int ks = 0; ks < 4; ++ks) {
    bf16x8 a[2];
#pragma unroll
    for (int m = 0; m < 2; ++m) {
      int row = s0 + wave * 32 + m * 16 + l15;
      a[m] = *reinterpret_cast<const bf16x8*>(sq + (size_t)row * HID + h * HD +
                                              ks * 32 + g * 8);
    }
#pragma unroll
    for (int n = 0; n < 8; ++n) {
      int rr = n * 16 + l15;
      int off = (rr * 256 + (ks * 32 + g * 8) * 2) ^ ((rr & 7) << 4);
      bf16x8 b = *reinterpret_cast<bf16x8*>(reinterpret_cast<char*>(mt_s) + off);
#pragma unroll
      for (int m = 0; m < 2; ++m)
        acc[m][n] =
            __builtin_amdgcn_mfma_f32_16x16x32_bf16(a[m], b, acc[m][n], 0, 0, 0);
    }
  }

  float den[2][4];
#pragma unroll
  for (int m = 0; m < 2; ++m)
#pragma unroll
    for (int r = 0; r < 4; ++r) {
      int row = s0 + wave * 32 + m * 16 + g * 4 + r;
      bf16x8 sv = *reinterpret_cast<const bf16x8*>(sq + (size_t)row * HID +
                                                   h * HD + l15 * 8);
      float part = 0.0f;
#pragma unroll
      for (int j = 0; j < 8; ++j) part += bf2f(sv[j]) * z[h * HD + l15 * 8 + j];
      part += __shfl_xor(part, 1);
      part += __shfl_xor(part, 2);
      part += __shfl_xor(part, 4);
      part += __shfl_xor(part, 8);
      den[m][r] = part + 1e-8f;
    }
  float gv = 1.0f / (1.0f + expf(-beta[0]));
#pragma unroll
  for (int m = 0; m < 2; ++m)
#pragma unroll
    for (int n = 0; n < 8; ++n)
#pragma unroll
      for (int r = 0; r < 4; ++r) {
        int row = s0 + wave * 32 + m * 16 + g * 4 + r;
        int col = n * 16 + l15;
        float mem = acc[m][n][r] / den[m][r];
        float at = attn[(size_t)row * HID + h * HD + col];
        combined[(size_t)row * HID + h * HD + col] =
            f2bf(gv * mem + (1.0f - gv) * at);
      }
}

// --------------------------- M_new (split-K) --------------------------------
__global__ __launch_bounds__(256) void mnew_part_kernel(
    const short* __restrict__ skT, const short* __restrict__ vT,
    float* __restrict__ part) {
  const int sp = blockIdx.x;  // 0..7
  const int h = blockIdx.y;
  const int tid = threadIdx.x;
  const int wave = tid >> 6, lane = tid & 63;
  const int g = lane >> 4, l15 = lane & 15;
  f32x4 acc[2][8] = {};
  for (int ks = sp * 8; ks < sp * 8 + 8; ++ks) {
    bf16x8 a[2];
#pragma unroll
    for (int m = 0; m < 2; ++m) {
      int dd = wave * 32 + m * 16 + l15;
      a[m] = *reinterpret_cast<const bf16x8*>(skT + (size_t)(h * HD + dd) * S_LEN +
                                              ks * 32 + g * 8);
    }
#pragma unroll
    for (int n = 0; n < 8; ++n) {
      int e = n * 16 + l15;
      bf16x8 b = *reinterpret_cast<const bf16x8*>(
          vT + (size_t)(h * HD + e) * S_LEN + ks * 32 + g * 8);
#pragma unroll
      for (int m = 0; m < 2; ++m)
        acc[m][n] =
            __builtin_amdgcn_mfma_f32_16x16x32_bf16(a[m], b, acc[m][n], 0, 0, 0);
    }
  }
#pragma unroll
  for (int m = 0; m < 2; ++m)
#pragma unroll
    for (int n = 0; n < 8; ++n)
#pragma unroll
      for (int r = 0; r < 4; ++r) {
        int dd = wave * 32 + m * 16 + g * 4 + r;
        int e = n * 16 + l15;
        part[(size_t)(sp * 16 + h) * 16384 + (size_t)dd * 128 + e] =
            acc[m][n][r];
      }
}

__global__ __launch_bounds__(256) void mnew_reduce_kernel(
    const float* __restrict__ part, const float* __restrict__ Mold,
    float* __restrict__ Mout) {
  int idx = blockIdx.x * 256 + threadIdx.x;  // 65536 threads
  int j4 = idx * 4;
  int h = j4 >> 14;
  int rem = j4 & 16383;
  float4 a = *reinterpret_cast<const float4*>(Mold + j4);
#pragma unroll
  for (int s = 0; s < 8; ++s) {
    float4 p = *reinterpret_cast<const float4*>(
        part + ((size_t)(s * 16 + h) << 14) + rem);
    a.x += p.x;
    a.y += p.y;
    a.z += p.z;
    a.w += p.w;
  }
  *reinterpret_cast<float4*>(Mout + j4) = a;
}

// --------------------------- z_new -----------------------------------------
__global__ __launch_bounds__(256) void znew_kernel(const short* __restrict__ skT,
                                                   const float* __restrict__ z,
                                                   float* __restrict__ out) {
  int row = blockIdx.x;
  int tid = threadIdx.x;
  bf16x8 vv = *reinterpret_cast<const bf16x8*>(skT + (size_t)row * S_LEN + tid * 8);
  float s = 0.0f;
#pragma unroll
  for (int j = 0; j < 8; ++j) s += bf2f(vv[j]);
#pragma unroll
  for (int off = 1; off < 64; off <<= 1) s += __shfl_xor(s, off);
  __shared__ float wsum[4];
  if ((tid & 63) == 0) wsum[tid >> 6] = s;
  __syncthreads();
  if (tid == 0) out[row] = z[row] + wsum[0] + wsum[1] + wsum[2] + wsum[3];
}

// ---------------------------------------------------------------------------
extern "C" void kernel_launch(void* const* d_in, const int* in_sizes, int n_in,
                              void* d_out, int out_size, void* d_ws,
                              size_t ws_size, hipStream_t stream) {
  const float* hs = (const float*)d_in[0];
  const int* pos = (const int*)d_in[2];
  const float* Wq = (const float*)d_in[3];
  const float* bq = (const float*)d_in[4];
  const float* Wk = (const float*)d_in[5];
  const float* bk = (const float*)d_in[6];
  const float* Wo = (const float*)d_in[7];
  const float* beta = (const float*)d_in[8];
  const float* Mm = (const float*)d_in[9];
  const float* z = (const float*)d_in[10];
  float* out = (float*)d_out;

  char* ws = (char*)d_ws;
  const size_t MB = 1u << 20;
  float* q_f32 = (float*)(ws + 0);         // 16MB ; -> attn ; -> mnew partials
  float* k_f32 = (float*)(ws + 16 * MB);   // 16MB ; -> comb after rope
  short* hs_b = (short*)(ws + 32 * MB);    // 8MB  ; -> sk after fused GEMM
  short* WqkT = (short*)(ws + 40 * MB);    // 16MB ; -> v/skT after fused GEMM
  short* WoT = (short*)(ws + 56 * MB);     // 8MB
  short* qr = (short*)(ws + 64 * MB);      // 8MB
  short* kr = (short*)(ws + 72 * MB);      // 8MB
  short* sq = (short*)(ws + 80 * MB);      // 8MB
  short* vT = (short*)(ws + 88 * MB);      // 8MB
  short* MT = (short*)(ws + 96 * MB);      // 512KB
  float* cost = (float*)(ws + 96 * MB + 512 * 1024);  // 512KB
  float* sint = (float*)(ws + 97 * MB);               // 512KB
  float* attn = q_f32;
  short* comb = (short*)k_f32;
  short* sk = hs_b;
  short* v = WqkT;
  short* skT = WqkT + 4 * 1024 * 1024;
  float* mpart = q_f32;  // 8MB partials; attn dead after mem_combine

  f32_to_bf16_kernel<<<2048, 256, 0, stream>>>(hs, hs_b);
  transpose_f2b_kernel<<<dim3(64, 64, 1), 256, 0, stream>>>(Wq, WqkT, 2048, 2048);
  transpose_f2b_kernel<<<dim3(64, 64, 1), 256, 0, stream>>>(
      Wk, WqkT + 4 * 1024 * 1024, 2048, 2048);
  transpose_f2b_kernel<<<dim3(64, 64, 1), 256, 0, stream>>>(Wo, WoT, 2048, 2048);
  transpose_f2b_kernel<<<dim3(4, 4, 16), 256, 0, stream>>>(Mm, MT, 128, 128);
  tables_kernel<<<512, 256, 0, stream>>>(pos, cost, sint);

  gemm_bt_dual_kernel<<<dim3(16, 32), 256, 0, stream>>>(hs_b, WqkT, bq, bk,
                                                        q_f32, k_f32);
  rope_kernel<<<2048, 256, 0, stream>>>(q_f32, k_f32, cost, sint, qr, kr, sq, sk,
                                        v);
  transpose_b2b_kernel<<<dim3(64, 64, 1), 256, 0, stream>>>(v, vT, 2048, 2048);
  transpose_b2b_kernel<<<dim3(64, 64, 1), 256, 0, stream>>>(sk, skT, 2048, 2048);

  attn_kernel<<<512, 256, 0, stream>>>(qr, kr, vT, attn);
  mem_combine_kernel<<<dim3(16, 16), 256, 0, stream>>>(sq, MT, z, attn, beta,
                                                       comb);
  gemm_bt_dual_kernel<<<dim3(16, 16), 256, 0, stream>>>(comb, WoT, nullptr,
                                                        nullptr, out, out);
  mnew_part_kernel<<<dim3(8, 16), 256, 0, stream>>>(skT, vT, mpart);
  mnew_reduce_kernel<<<256, 256, 0, stream>>>(mpart, Mm, out + 4194304);
  znew_kernel<<<2048, 256, 0, stream>>>(skT, z, out + 4194304 + 16 * 128 * 128);
}

// Round 5
// 410.000 us; speedup vs baseline: 1.4084x; 1.0803x over previous
//
#include <hip/hip_runtime.h>
#include <hip/hip_bf16.h>

// ---------------------------------------------------------------------------
// InfiniAttention on MI355X — round 5.
// R4 profile: attn 137us, MfmaUtil 5%, VALU 13%, occ 10% -> latency-bound:
// per-tile global-load latency fully exposed (loads at loop top, 2 barriers).
// R5: attn KVBLK=64 double-buffered, issue-early loads, ONE barrier/tile,
//     mask only on diagonal tile, mem_combine fused into attn epilogue.
// ---------------------------------------------------------------------------

#define S_LEN 2048
#define HID 2048
#define NH 16
#define HD 128
#define SCALE_QK 0.088388347648318447f

typedef __attribute__((ext_vector_type(8))) short bf16x8;
typedef __attribute__((ext_vector_type(4))) float f32x4;

__device__ __forceinline__ short f2bf(float f) {
  __hip_bfloat16 h = __float2bfloat16(f);
  return __builtin_bit_cast(short, h);
}
__device__ __forceinline__ float bf2f(short s) {
  unsigned int u = ((unsigned int)(unsigned short)s) << 16;
  return __builtin_bit_cast(float, u);
}
__device__ __forceinline__ void gload16(const void* g, void* l) {
  __builtin_amdgcn_global_load_lds(
      (const __attribute__((address_space(1))) void*)g,
      (__attribute__((address_space(3))) void*)l, 16, 0, 0);
}

// --------------------------- elementwise convert ---------------------------
__global__ __launch_bounds__(256) void f32_to_bf16_kernel(
    const float* __restrict__ in, short* __restrict__ out) {
  size_t i = (size_t)(blockIdx.x * 256 + threadIdx.x) * 8;
  float4 a = *reinterpret_cast<const float4*>(in + i);
  float4 b = *reinterpret_cast<const float4*>(in + i + 4);
  alignas(16) short t[8] = {f2bf(a.x), f2bf(a.y), f2bf(a.z), f2bf(a.w),
                            f2bf(b.x), f2bf(b.y), f2bf(b.z), f2bf(b.w)};
  *reinterpret_cast<int4*>(out + i) = *reinterpret_cast<int4*>(t);
}

// --------------------------- transposes ------------------------------------
__global__ __launch_bounds__(256) void transpose_f2b_kernel(
    const float* __restrict__ in, short* __restrict__ out, int R, int C) {
  __shared__ float t[32][33];
  size_t bo = (size_t)blockIdx.z * R * C;
  int r0 = blockIdx.y * 32, c0 = blockIdx.x * 32;
  int tx = threadIdx.x & 31, ty = threadIdx.x >> 5;
#pragma unroll
  for (int i = 0; i < 4; ++i)
    t[ty + i * 8][tx] = in[bo + (size_t)(r0 + ty + i * 8) * C + c0 + tx];
  __syncthreads();
#pragma unroll
  for (int i = 0; i < 4; ++i)
    out[bo + (size_t)(c0 + ty + i * 8) * R + r0 + tx] = f2bf(t[tx][ty + i * 8]);
}

__global__ __launch_bounds__(256) void transpose_b2b_kernel(
    const short* __restrict__ in, short* __restrict__ out, int R, int C) {
  __shared__ short t[32][33];
  int r0 = blockIdx.y * 32, c0 = blockIdx.x * 32;
  int tx = threadIdx.x & 31, ty = threadIdx.x >> 5;
#pragma unroll
  for (int i = 0; i < 4; ++i)
    t[ty + i * 8][tx] = in[(size_t)(r0 + ty + i * 8) * C + c0 + tx];
  __syncthreads();
#pragma unroll
  for (int i = 0; i < 4; ++i)
    out[(size_t)(c0 + ty + i * 8) * R + r0 + tx] = t[tx][ty + i * 8];
}

// --------------------------- rope tables -----------------------------------
__global__ __launch_bounds__(256) void tables_kernel(
    const int* __restrict__ pos_ids, float* __restrict__ cost,
    float* __restrict__ sint) {
  int idx = blockIdx.x * 256 + threadIdx.x;
  int s = idx >> 6, j = idx & 63;
  float pos = (float)pos_ids[s];
  float inv = powf(10000.0f, -((float)j) / 64.0f);
  float a = pos * inv;
  cost[idx] = cosf(a);
  sint[idx] = sinf(a);
}

// --------------------------- GEMM (m97 structure, dual output) --------------
__global__ __launch_bounds__(256) void gemm_bt_dual_kernel(
    const short* __restrict__ A, const short* __restrict__ BT,
    const float* __restrict__ bias0, const float* __restrict__ bias1,
    float* __restrict__ C0, float* __restrict__ C1) {
  __shared__ short As[128 * 64];
  __shared__ short Bs[128 * 64];
  const int K = 2048;
  const int tid = threadIdx.x;
  const int wave = tid >> 6, lane = tid & 63;
  const int g = lane >> 4, l15 = lane & 15;
  const int wm = (wave >> 1) * 64, wn = (wave & 1) * 64;
  const int row0 = blockIdx.x * 128;
  const int colg0 = blockIdx.y * 128;

  const int ld_r = wave * 32 + (lane >> 3);
  const int ld_c = (lane & 7) * 8;
  const short* Ag = A + (size_t)(row0 + ld_r) * K + ld_c;
  const short* Bg = BT + (size_t)(colg0 + ld_r) * K + ld_c;
  short* Al = As + wave * 2048;
  short* Bl = Bs + wave * 2048;

  f32x4 acc[4][4] = {};
  for (int kt = 0; kt < K; kt += 64) {
    __syncthreads();
#pragma unroll
    for (int i = 0; i < 4; ++i) {
      gload16(Ag + kt + (size_t)i * 8 * K, Al + i * 512);
      gload16(Bg + kt + (size_t)i * 8 * K, Bl + i * 512);
    }
    __syncthreads();
#pragma unroll
    for (int ks = 0; ks < 2; ++ks) {
      bf16x8 a[4], b[4];
#pragma unroll
      for (int m = 0; m < 4; ++m)
        a[m] = *reinterpret_cast<bf16x8*>(
            reinterpret_cast<char*>(As) + (wm + m * 16 + l15) * 128 +
            (ks * 32 + g * 8) * 2);
#pragma unroll
      for (int n = 0; n < 4; ++n)
        b[n] = *reinterpret_cast<bf16x8*>(
            reinterpret_cast<char*>(Bs) + (wn + n * 16 + l15) * 128 +
            (ks * 32 + g * 8) * 2);
#pragma unroll
      for (int m = 0; m < 4; ++m)
#pragma unroll
        for (int n = 0; n < 4; ++n)
          acc[m][n] = __builtin_amdgcn_mfma_f32_16x16x32_bf16(a[m], b[n],
                                                              acc[m][n], 0, 0, 0);
    }
  }

  float* C = (colg0 < 2048) ? C0 : C1;
  const float* bias = (colg0 < 2048) ? bias0 : bias1;
  const int col0 = (colg0 < 2048) ? colg0 : colg0 - 2048;
#pragma unroll
  for (int m = 0; m < 4; ++m)
#pragma unroll
    for (int n = 0; n < 4; ++n) {
      int row = row0 + wm + m * 16 + g * 4;
      int col = col0 + wn + n * 16 + l15;
      float bv = bias ? bias[col] : 0.0f;
#pragma unroll
      for (int r = 0; r < 4; ++r)
        C[(size_t)(row + r) * 2048 + col] = acc[m][n][r] + bv;
    }
}

// --------------------------- rope / elu ------------------------------------
__global__ __launch_bounds__(256) void rope_kernel(
    const float* __restrict__ qf, const float* __restrict__ kf,
    const float* __restrict__ cost, const float* __restrict__ sint,
    short* __restrict__ qr, short* __restrict__ kr, short* __restrict__ sq,
    short* __restrict__ sk, short* __restrict__ v) {
  int s = blockIdx.x;
  int hd = threadIdx.x * 8;
  int d = hd & 127;
  bool lo = d < 64;
  size_t base = (size_t)s * HID + hd;
  size_t pb = lo ? base + 64 : base - 64;
  int tb = s * 64 + (hd & 63);
  alignas(16) short oqr[8], okr[8], osq[8], osk[8], ov[8];
#pragma unroll
  for (int j = 0; j < 8; ++j) {
    float c = cost[tb + j], sn = sint[tb + j];
    float q = qf[base + j], qp = qf[pb + j];
    float k = kf[base + j], kp = kf[pb + j];
    float rq = lo ? -qp : qp;
    float rk = lo ? -kp : kp;
    float qrv = q * c + rq * sn;
    float krv = k * c + rk * sn;
    oqr[j] = f2bf(qrv);
    okr[j] = f2bf(krv);
    osq[j] = f2bf(qrv > 0.0f ? qrv + 1.0f : __expf(qrv));
    osk[j] = f2bf(krv > 0.0f ? krv + 1.0f : __expf(krv));
    ov[j] = f2bf(q);
  }
  *reinterpret_cast<int4*>(qr + base) = *reinterpret_cast<int4*>(oqr);
  *reinterpret_cast<int4*>(kr + base) = *reinterpret_cast<int4*>(okr);
  *reinterpret_cast<int4*>(sq + base) = *reinterpret_cast<int4*>(osq);
  *reinterpret_cast<int4*>(sk + base) = *reinterpret_cast<int4*>(osk);
  *reinterpret_cast<int4*>(v + base) = *reinterpret_cast<int4*>(ov);
}

// --------------------------- flash attention + mem combine ------------------
// 512 blocks = (h, qt 0..31 balanced). QBLK=64 (4 waves x 16 rows), KVBLK=64.
// Double-buffered K/V (72KB LDS -> 2 blk/CU), issue-early loads, 1 barrier/tile.
// Epilogue: MT[h] into dead K bufs, sq@M + den + sigmoid-gate combine -> comb.
__global__ __launch_bounds__(256) void attn_kernel(
    const short* __restrict__ qr, const short* __restrict__ kr,
    const short* __restrict__ vT, const short* __restrict__ sq,
    const short* __restrict__ MT, const float* __restrict__ z,
    const float* __restrict__ beta, short* __restrict__ comb) {
  __shared__ short k_s[2][64 * 128];  // 2 x 16KB  [t][d]
  __shared__ short v_s[2][128 * 64];  // 2 x 16KB  [d][t]
  __shared__ short p_s[4][16 * 64];   // 8KB, per-wave [q][t]
  const int tid = threadIdx.x;
  const int wave = tid >> 6, lane = tid & 63;
  const int g = lane >> 4, l15 = lane & 15;
  const int bid = blockIdx.x;
  const int h = bid & 15;
  const int u = bid >> 4;
  const int qt = (u < 16) ? (2 * u) : (31 - 2 * (u - 16));
  const int q0 = qt * 64;
  const int ntiles = qt + 1;

  bf16x8 qf[4];
#pragma unroll
  for (int ks = 0; ks < 4; ++ks) {
    int row = q0 + wave * 16 + l15;
    qf[ks] = *reinterpret_cast<const bf16x8*>(qr + (size_t)row * HID + h * HD +
                                              ks * 32 + g * 8);
  }

  int4 kreg[4], vreg[4];
#define LOAD_TILE(T0)                                                         \
  {                                                                           \
    _Pragma("unroll") for (int i = 0; i < 4; ++i) {                           \
      int c = tid + 256 * i;                                                  \
      kreg[i] = *reinterpret_cast<const int4*>(                               \
          kr + (size_t)((T0) + (c >> 4)) * HID + h * HD + (c & 15) * 8);      \
      vreg[i] = *reinterpret_cast<const int4*>(                               \
          vT + (size_t)(h * HD + (c >> 3)) * S_LEN + (T0) + (c & 7) * 8);     \
    }                                                                         \
  }
#define WRITE_TILE(B)                                                         \
  {                                                                           \
    _Pragma("unroll") for (int i = 0; i < 4; ++i) {                           \
      int c = tid + 256 * i;                                                  \
      int rk = c >> 4, ck = c & 15;                                           \
      *reinterpret_cast<int4*>(reinterpret_cast<char*>(k_s[B]) +              \
                               ((rk * 256 + ck * 16) ^ ((rk & 7) << 4))) =    \
          kreg[i];                                                            \
      int rv = c >> 3, cv = c & 7;                                            \
      *reinterpret_cast<int4*>(reinterpret_cast<char*>(v_s[B]) +              \
                               ((rv * 128 + cv * 16) ^ ((rv & 7) << 4))) =    \
          vreg[i];                                                            \
    }                                                                         \
  }

  LOAD_TILE(0);
  WRITE_TILE(0);
  __syncthreads();

  f32x4 o[8] = {};
  float m_run[4], l_run[4];
#pragma unroll
  for (int r = 0; r < 4; ++r) {
    m_run[r] = -3.0e38f;
    l_run[r] = 0.0f;
  }

  for (int kt = 0; kt < ntiles; ++kt) {
    const int cur = kt & 1;
    if (kt + 1 < ntiles) LOAD_TILE((kt + 1) * 64);  // issue early, hide latency

    // QK^T: 4 t-frags x 4 k-steps
    f32x4 sfr[4] = {};
#pragma unroll
    for (int n = 0; n < 4; ++n) {
#pragma unroll
      for (int ks = 0; ks < 4; ++ks) {
        int rr = n * 16 + l15;
        int off = (rr * 256 + (ks * 32 + g * 8) * 2) ^ ((rr & 7) << 4);
        bf16x8 b =
            *reinterpret_cast<bf16x8*>(reinterpret_cast<char*>(k_s[cur]) + off);
        sfr[n] = __builtin_amdgcn_mfma_f32_16x16x32_bf16(qf[ks], b, sfr[n], 0,
                                                         0, 0);
      }
    }

    const bool diag = (kt == qt);  // wave-uniform
#pragma unroll
    for (int r = 0; r < 4; ++r) {
      const int srow = q0 + wave * 16 + g * 4 + r;
      float mx = m_run[r];
#pragma unroll
      for (int n = 0; n < 4; ++n) {
        float val = sfr[n][r] * SCALE_QK;
        if (diag) {
          int t = kt * 64 + n * 16 + l15;
          val = (t <= srow) ? val : -3.0e38f;
        }
        sfr[n][r] = val;
        mx = fmaxf(mx, val);
      }
      mx = fmaxf(mx, __shfl_xor(mx, 1));
      mx = fmaxf(mx, __shfl_xor(mx, 2));
      mx = fmaxf(mx, __shfl_xor(mx, 4));
      mx = fmaxf(mx, __shfl_xor(mx, 8));
      float sum = 0.0f;
#pragma unroll
      for (int n = 0; n < 4; ++n) {
        float p = __expf(sfr[n][r] - mx);
        sfr[n][r] = p;
        sum += p;
      }
      sum += __shfl_xor(sum, 1);
      sum += __shfl_xor(sum, 2);
      sum += __shfl_xor(sum, 4);
      sum += __shfl_xor(sum, 8);
      float f = __expf(m_run[r] - mx);
      l_run[r] = l_run[r] * f + sum;
      m_run[r] = mx;
#pragma unroll
      for (int n = 0; n < 8; ++n) o[n][r] *= f;
    }

    // P -> bf16 -> wave-private swizzled LDS (16 x 64)
    char* pw = reinterpret_cast<char*>(p_s[wave]);
#pragma unroll
    for (int n = 0; n < 4; ++n)
#pragma unroll
      for (int r = 0; r < 4; ++r) {
        int rl = g * 4 + r;
        int off = (rl * 128 + (n * 16 + l15) * 2) ^ ((rl & 7) << 4);
        *reinterpret_cast<short*>(pw + off) = f2bf(sfr[n][r]);
      }

    // PV: 2 k-steps over t, 8 d-frags
#pragma unroll
    for (int ks = 0; ks < 2; ++ks) {
      int offp = (l15 * 128 + (ks * 32 + g * 8) * 2) ^ ((l15 & 7) << 4);
      bf16x8 pa = *reinterpret_cast<bf16x8*>(pw + offp);
#pragma unroll
      for (int n = 0; n < 8; ++n) {
        int rr = n * 16 + l15;
        int off = (rr * 128 + (ks * 32 + g * 8) * 2) ^ ((rr & 7) << 4);
        bf16x8 vb =
            *reinterpret_cast<bf16x8*>(reinterpret_cast<char*>(v_s[cur]) + off);
        o[n] = __builtin_amdgcn_mfma_f32_16x16x32_bf16(pa, vb, o[n], 0, 0, 0);
      }
    }

    if (kt + 1 < ntiles) WRITE_TILE(cur ^ 1);  // other buffer: no race
    __syncthreads();
  }
#undef LOAD_TILE
#undef WRITE_TILE

  // ---------------- epilogue: mem path + gate combine ----------------
  // stage MT[h] (128x128 bf16 = 32KB) into k_s space (dead now)
  short* mt_s = &k_s[0][0];
#pragma unroll
  for (int i = 0; i < 8; ++i) {
    int c = tid + 256 * i;
    int r = c >> 4, kc = c & 15;
    int4 d = *reinterpret_cast<const int4*>(MT + (size_t)h * 16384 + r * 128 +
                                            kc * 8);
    *reinterpret_cast<int4*>(reinterpret_cast<char*>(mt_s) +
                             ((r * 256 + kc * 16) ^ ((r & 7) << 4))) = d;
  }
  __syncthreads();

  bf16x8 af[4];
#pragma unroll
  for (int ks = 0; ks < 4; ++ks) {
    int row = q0 + wave * 16 + l15;
    af[ks] = *reinterpret_cast<const bf16x8*>(sq + (size_t)row * HID + h * HD +
                                              ks * 32 + g * 8);
  }
  f32x4 acc2[8] = {};
#pragma unroll
  for (int ks = 0; ks < 4; ++ks) {
#pragma unroll
    for (int n = 0; n < 8; ++n) {
      int rr = n * 16 + l15;
      int off = (rr * 256 + (ks * 32 + g * 8) * 2) ^ ((rr & 7) << 4);
      bf16x8 b =
          *reinterpret_cast<bf16x8*>(reinterpret_cast<char*>(mt_s) + off);
      acc2[n] = __builtin_amdgcn_mfma_f32_16x16x32_bf16(af[ks], b, acc2[n], 0,
                                                        0, 0);
    }
  }

  float den[4];
#pragma unroll
  for (int r = 0; r < 4; ++r) {
    int row = q0 + wave * 16 + g * 4 + r;
    bf16x8 sv =
        *reinterpret_cast<const bf16x8*>(sq + (size_t)row * HID + h * HD +
                                         l15 * 8);
    float part = 0.0f;
#pragma unroll
    for (int j = 0; j < 8; ++j) part += bf2f(sv[j]) * z[h * HD + l15 * 8 + j];
    part += __shfl_xor(part, 1);
    part += __shfl_xor(part, 2);
    part += __shfl_xor(part, 4);
    part += __shfl_xor(part, 8);
    den[r] = part + 1e-8f;
  }

  float gv = 1.0f / (1.0f + __expf(-beta[0]));
#pragma unroll
  for (int n = 0; n < 8; ++n)
#pragma unroll
    for (int r = 0; r < 4; ++r) {
      int row = q0 + wave * 16 + g * 4 + r;
      int col = n * 16 + l15;
      float mem = acc2[n][r] / den[r];
      float at = o[n][r] / l_run[r];
      comb[(size_t)row * HID + h * HD + col] = f2bf(gv * mem + (1.0f - gv) * at);
    }
}

// --------------------------- M_new (split-K) --------------------------------
__global__ __launch_bounds__(256) void mnew_part_kernel(
    const short* __restrict__ skT, const short* __restrict__ vT,
    float* __restrict__ part) {
  const int sp = blockIdx.x;  // 0..7
  const int h = blockIdx.y;
  const int tid = threadIdx.x;
  const int wave = tid >> 6, lane = tid & 63;
  const int g = lane >> 4, l15 = lane & 15;
  f32x4 acc[2][8] = {};
  for (int ks = sp * 8; ks < sp * 8 + 8; ++ks) {
    bf16x8 a[2];
#pragma unroll
    for (int m = 0; m < 2; ++m) {
      int dd = wave * 32 + m * 16 + l15;
      a[m] = *reinterpret_cast<const bf16x8*>(skT + (size_t)(h * HD + dd) * S_LEN +
                                              ks * 32 + g * 8);
    }
#pragma unroll
    for (int n = 0; n < 8; ++n) {
      int e = n * 16 + l15;
      bf16x8 b = *reinterpret_cast<const bf16x8*>(
          vT + (size_t)(h * HD + e) * S_LEN + ks * 32 + g * 8);
#pragma unroll
      for (int m = 0; m < 2; ++m)
        acc[m][n] =
            __builtin_amdgcn_mfma_f32_16x16x32_bf16(a[m], b, acc[m][n], 0, 0, 0);
    }
  }
#pragma unroll
  for (int m = 0; m < 2; ++m)
#pragma unroll
    for (int n = 0; n < 8; ++n)
#pragma unroll
      for (int r = 0; r < 4; ++r) {
        int dd = wave * 32 + m * 16 + g * 4 + r;
        int e = n * 16 + l15;
        part[(size_t)(sp * 16 + h) * 16384 + (size_t)dd * 128 + e] =
            acc[m][n][r];
      }
}

__global__ __launch_bounds__(256) void mnew_reduce_kernel(
    const float* __restrict__ part, const float* __restrict__ Mold,
    float* __restrict__ Mout) {
  int idx = blockIdx.x * 256 + threadIdx.x;
  int j4 = idx * 4;
  int h = j4 >> 14;
  int rem = j4 & 16383;
  float4 a = *reinterpret_cast<const float4*>(Mold + j4);
#pragma unroll
  for (int s = 0; s < 8; ++s) {
    float4 p = *reinterpret_cast<const float4*>(
        part + ((size_t)(s * 16 + h) << 14) + rem);
    a.x += p.x;
    a.y += p.y;
    a.z += p.z;
    a.w += p.w;
  }
  *reinterpret_cast<float4*>(Mout + j4) = a;
}

// --------------------------- z_new -----------------------------------------
__global__ __launch_bounds__(256) void znew_kernel(const short* __restrict__ skT,
                                                   const float* __restrict__ z,
                                                   float* __restrict__ out) {
  int row = blockIdx.x;
  int tid = threadIdx.x;
  bf16x8 vv = *reinterpret_cast<const bf16x8*>(skT + (size_t)row * S_LEN + tid * 8);
  float s = 0.0f;
#pragma unroll
  for (int j = 0; j < 8; ++j) s += bf2f(vv[j]);
#pragma unroll
  for (int off = 1; off < 64; off <<= 1) s += __shfl_xor(s, off);
  __shared__ float wsum[4];
  if ((tid & 63) == 0) wsum[tid >> 6] = s;
  __syncthreads();
  if (tid == 0) out[row] = z[row] + wsum[0] + wsum[1] + wsum[2] + wsum[3];
}

// ---------------------------------------------------------------------------
extern "C" void kernel_launch(void* const* d_in, const int* in_sizes, int n_in,
                              void* d_out, int out_size, void* d_ws,
                              size_t ws_size, hipStream_t stream) {
  const float* hs = (const float*)d_in[0];
  const int* pos = (const int*)d_in[2];
  const float* Wq = (const float*)d_in[3];
  const float* bq = (const float*)d_in[4];
  const float* Wk = (const float*)d_in[5];
  const float* bk = (const float*)d_in[6];
  const float* Wo = (const float*)d_in[7];
  const float* beta = (const float*)d_in[8];
  const float* Mm = (const float*)d_in[9];
  const float* z = (const float*)d_in[10];
  float* out = (float*)d_out;

  char* ws = (char*)d_ws;
  const size_t MB = 1u << 20;
  float* q_f32 = (float*)(ws + 0);         // 16MB ; -> mnew partials later
  float* k_f32 = (float*)(ws + 16 * MB);   // 16MB ; -> comb after rope
  short* hs_b = (short*)(ws + 32 * MB);    // 8MB  ; -> sk after fused GEMM
  short* WqkT = (short*)(ws + 40 * MB);    // 16MB ; -> v/skT after fused GEMM
  short* WoT = (short*)(ws + 56 * MB);     // 8MB
  short* qr = (short*)(ws + 64 * MB);      // 8MB
  short* kr = (short*)(ws + 72 * MB);      // 8MB
  short* sq = (short*)(ws + 80 * MB);      // 8MB
  short* vT = (short*)(ws + 88 * MB);      // 8MB
  short* MT = (short*)(ws + 96 * MB);      // 512KB
  float* cost = (float*)(ws + 96 * MB + 512 * 1024);  // 512KB
  float* sint = (float*)(ws + 97 * MB);               // 512KB
  short* comb = (short*)k_f32;
  short* sk = hs_b;
  short* v = WqkT;
  short* skT = WqkT + 4 * 1024 * 1024;
  float* mpart = q_f32;  // 8MB partials (q_f32 dead after rope)

  f32_to_bf16_kernel<<<2048, 256, 0, stream>>>(hs, hs_b);
  transpose_f2b_kernel<<<dim3(64, 64, 1), 256, 0, stream>>>(Wq, WqkT, 2048, 2048);
  transpose_f2b_kernel<<<dim3(64, 64, 1), 256, 0, stream>>>(
      Wk, WqkT + 4 * 1024 * 1024, 2048, 2048);
  transpose_f2b_kernel<<<dim3(64, 64, 1), 256, 0, stream>>>(Wo, WoT, 2048, 2048);
  transpose_f2b_kernel<<<dim3(4, 4, 16), 256, 0, stream>>>(Mm, MT, 128, 128);
  tables_kernel<<<512, 256, 0, stream>>>(pos, cost, sint);

  gemm_bt_dual_kernel<<<dim3(16, 32), 256, 0, stream>>>(hs_b, WqkT, bq, bk,
                                                        q_f32, k_f32);
  rope_kernel<<<2048, 256, 0, stream>>>(q_f32, k_f32, cost, sint, qr, kr, sq, sk,
                                        v);
  transpose_b2b_kernel<<<dim3(64, 64, 1), 256, 0, stream>>>(v, vT, 2048, 2048);
  transpose_b2b_kernel<<<dim3(64, 64, 1), 256, 0, stream>>>(sk, skT, 2048, 2048);

  attn_kernel<<<512, 256, 0, stream>>>(qr, kr, vT, sq, MT, z, beta, comb);
  gemm_bt_dual_kernel<<<dim3(16, 16), 256, 0, stream>>>(comb, WoT, nullptr,
                                                        nullptr, out, out);
  mnew_part_kernel<<<dim3(8, 16), 256, 0, stream>>>(skT, vT, mpart);
  mnew_reduce_kernel<<<256, 256, 0, stream>>>(mpart, Mm, out + 4194304);
  znew_kernel<<<2048, 256, 0, stream>>>(skT, z, out + 4194304 + 16 * 128 * 128);
}

// Round 6
// 362.145 us; speedup vs baseline: 1.5945x; 1.1321x over previous
//
#include <hip/hip_runtime.h>
#include <hip/hip_bf16.h>

// ---------------------------------------------------------------------------
// InfiniAttention on MI355X — round 6.
// R5 failure: reg-staged K/V double-buffer spilled to scratch (WRITE_SIZE
// 86MB vs 8MB output) -> per-tile scratch latency serialized; attn stuck 134us.
// R6: global_load_lds direct staging with inverse-swizzled per-lane SOURCE
// (linear LDS dest, rule #21/m173), 1 barrier/tile, setprio(1) around MFMA.
// ---------------------------------------------------------------------------

#define S_LEN 2048
#define HID 2048
#define NH 16
#define HD 128
#define SCALE_QK 0.088388347648318447f

typedef __attribute__((ext_vector_type(8))) short bf16x8;
typedef __attribute__((ext_vector_type(4))) float f32x4;

__device__ __forceinline__ short f2bf(float f) {
  __hip_bfloat16 h = __float2bfloat16(f);
  return __builtin_bit_cast(short, h);
}
__device__ __forceinline__ float bf2f(short s) {
  unsigned int u = ((unsigned int)(unsigned short)s) << 16;
  return __builtin_bit_cast(float, u);
}
__device__ __forceinline__ void gload16(const void* g, void* l) {
  __builtin_amdgcn_global_load_lds(
      (const __attribute__((address_space(1))) void*)g,
      (__attribute__((address_space(3))) void*)l, 16, 0, 0);
}

// --------------------------- elementwise convert ---------------------------
__global__ __launch_bounds__(256) void f32_to_bf16_kernel(
    const float* __restrict__ in, short* __restrict__ out) {
  size_t i = (size_t)(blockIdx.x * 256 + threadIdx.x) * 8;
  float4 a = *reinterpret_cast<const float4*>(in + i);
  float4 b = *reinterpret_cast<const float4*>(in + i + 4);
  alignas(16) short t[8] = {f2bf(a.x), f2bf(a.y), f2bf(a.z), f2bf(a.w),
                            f2bf(b.x), f2bf(b.y), f2bf(b.z), f2bf(b.w)};
  *reinterpret_cast<int4*>(out + i) = *reinterpret_cast<int4*>(t);
}

// --------------------------- transposes ------------------------------------
__global__ __launch_bounds__(256) void transpose_f2b_kernel(
    const float* __restrict__ in, short* __restrict__ out, int R, int C) {
  __shared__ float t[32][33];
  size_t bo = (size_t)blockIdx.z * R * C;
  int r0 = blockIdx.y * 32, c0 = blockIdx.x * 32;
  int tx = threadIdx.x & 31, ty = threadIdx.x >> 5;
#pragma unroll
  for (int i = 0; i < 4; ++i)
    t[ty + i * 8][tx] = in[bo + (size_t)(r0 + ty + i * 8) * C + c0 + tx];
  __syncthreads();
#pragma unroll
  for (int i = 0; i < 4; ++i)
    out[bo + (size_t)(c0 + ty + i * 8) * R + r0 + tx] = f2bf(t[tx][ty + i * 8]);
}

__global__ __launch_bounds__(256) void transpose_b2b_kernel(
    const short* __restrict__ in, short* __restrict__ out, int R, int C) {
  __shared__ short t[32][33];
  int r0 = blockIdx.y * 32, c0 = blockIdx.x * 32;
  int tx = threadIdx.x & 31, ty = threadIdx.x >> 5;
#pragma unroll
  for (int i = 0; i < 4; ++i)
    t[ty + i * 8][tx] = in[(size_t)(r0 + ty + i * 8) * C + c0 + tx];
  __syncthreads();
#pragma unroll
  for (int i = 0; i < 4; ++i)
    out[(size_t)(c0 + ty + i * 8) * R + r0 + tx] = t[tx][ty + i * 8];
}

// --------------------------- rope tables -----------------------------------
__global__ __launch_bounds__(256) void tables_kernel(
    const int* __restrict__ pos_ids, float* __restrict__ cost,
    float* __restrict__ sint) {
  int idx = blockIdx.x * 256 + threadIdx.x;
  int s = idx >> 6, j = idx & 63;
  float pos = (float)pos_ids[s];
  float inv = powf(10000.0f, -((float)j) / 64.0f);
  float a = pos * inv;
  cost[idx] = cosf(a);
  sint[idx] = sinf(a);
}

// --------------------------- GEMM (m97 structure, dual output) --------------
__global__ __launch_bounds__(256) void gemm_bt_dual_kernel(
    const short* __restrict__ A, const short* __restrict__ BT,
    const float* __restrict__ bias0, const float* __restrict__ bias1,
    float* __restrict__ C0, float* __restrict__ C1) {
  __shared__ short As[128 * 64];
  __shared__ short Bs[128 * 64];
  const int K = 2048;
  const int tid = threadIdx.x;
  const int wave = tid >> 6, lane = tid & 63;
  const int g = lane >> 4, l15 = lane & 15;
  const int wm = (wave >> 1) * 64, wn = (wave & 1) * 64;
  const int row0 = blockIdx.x * 128;
  const int colg0 = blockIdx.y * 128;

  const int ld_r = wave * 32 + (lane >> 3);
  const int ld_c = (lane & 7) * 8;
  const short* Ag = A + (size_t)(row0 + ld_r) * K + ld_c;
  const short* Bg = BT + (size_t)(colg0 + ld_r) * K + ld_c;
  short* Al = As + wave * 2048;
  short* Bl = Bs + wave * 2048;

  f32x4 acc[4][4] = {};
  for (int kt = 0; kt < K; kt += 64) {
    __syncthreads();
#pragma unroll
    for (int i = 0; i < 4; ++i) {
      gload16(Ag + kt + (size_t)i * 8 * K, Al + i * 512);
      gload16(Bg + kt + (size_t)i * 8 * K, Bl + i * 512);
    }
    __syncthreads();
#pragma unroll
    for (int ks = 0; ks < 2; ++ks) {
      bf16x8 a[4], b[4];
#pragma unroll
      for (int m = 0; m < 4; ++m)
        a[m] = *reinterpret_cast<bf16x8*>(
            reinterpret_cast<char*>(As) + (wm + m * 16 + l15) * 128 +
            (ks * 32 + g * 8) * 2);
#pragma unroll
      for (int n = 0; n < 4; ++n)
        b[n] = *reinterpret_cast<bf16x8*>(
            reinterpret_cast<char*>(Bs) + (wn + n * 16 + l15) * 128 +
            (ks * 32 + g * 8) * 2);
#pragma unroll
      for (int m = 0; m < 4; ++m)
#pragma unroll
        for (int n = 0; n < 4; ++n)
          acc[m][n] = __builtin_amdgcn_mfma_f32_16x16x32_bf16(a[m], b[n],
                                                              acc[m][n], 0, 0, 0);
    }
  }

  float* C = (colg0 < 2048) ? C0 : C1;
  const float* bias = (colg0 < 2048) ? bias0 : bias1;
  const int col0 = (colg0 < 2048) ? colg0 : colg0 - 2048;
#pragma unroll
  for (int m = 0; m < 4; ++m)
#pragma unroll
    for (int n = 0; n < 4; ++n) {
      int row = row0 + wm + m * 16 + g * 4;
      int col = col0 + wn + n * 16 + l15;
      float bv = bias ? bias[col] : 0.0f;
#pragma unroll
      for (int r = 0; r < 4; ++r)
        C[(size_t)(row + r) * 2048 + col] = acc[m][n][r] + bv;
    }
}

// --------------------------- rope / elu ------------------------------------
__global__ __launch_bounds__(256) void rope_kernel(
    const float* __restrict__ qf, const float* __restrict__ kf,
    const float* __restrict__ cost, const float* __restrict__ sint,
    short* __restrict__ qr, short* __restrict__ kr, short* __restrict__ sq,
    short* __restrict__ sk, short* __restrict__ v) {
  int s = blockIdx.x;
  int hd = threadIdx.x * 8;
  int d = hd & 127;
  bool lo = d < 64;
  size_t base = (size_t)s * HID + hd;
  size_t pb = lo ? base + 64 : base - 64;
  int tb = s * 64 + (hd & 63);
  alignas(16) short oqr[8], okr[8], osq[8], osk[8], ov[8];
#pragma unroll
  for (int j = 0; j < 8; ++j) {
    float c = cost[tb + j], sn = sint[tb + j];
    float q = qf[base + j], qp = qf[pb + j];
    float k = kf[base + j], kp = kf[pb + j];
    float rq = lo ? -qp : qp;
    float rk = lo ? -kp : kp;
    float qrv = q * c + rq * sn;
    float krv = k * c + rk * sn;
    oqr[j] = f2bf(qrv);
    okr[j] = f2bf(krv);
    osq[j] = f2bf(qrv > 0.0f ? qrv + 1.0f : __expf(qrv));
    osk[j] = f2bf(krv > 0.0f ? krv + 1.0f : __expf(krv));
    ov[j] = f2bf(q);
  }
  *reinterpret_cast<int4*>(qr + base) = *reinterpret_cast<int4*>(oqr);
  *reinterpret_cast<int4*>(kr + base) = *reinterpret_cast<int4*>(okr);
  *reinterpret_cast<int4*>(sq + base) = *reinterpret_cast<int4*>(osq);
  *reinterpret_cast<int4*>(sk + base) = *reinterpret_cast<int4*>(osk);
  *reinterpret_cast<int4*>(v + base) = *reinterpret_cast<int4*>(ov);
}

// --------------------------- flash attention + mem combine ------------------
// 512 blocks = (h, qt 0..31 balanced). QBLK=64 (4 waves x 16 rows), KVBLK=64.
// Double-buffered K/V staged via global_load_lds (linear dest + inverse-swizzled
// per-lane source), issue-early, 1 barrier/tile, setprio around MFMA.
// Epilogue: MT[h] into dead K bufs, sq@M + den + sigmoid-gate combine -> comb.
__global__ __launch_bounds__(256) void attn_kernel(
    const short* __restrict__ qr, const short* __restrict__ kr,
    const short* __restrict__ vT, const short* __restrict__ sq,
    const short* __restrict__ MT, const float* __restrict__ z,
    const float* __restrict__ beta, short* __restrict__ comb) {
  __shared__ short k_s[2][64 * 128];  // 2 x 16KB  [t][d], XOR-swizzled
  __shared__ short v_s[2][128 * 64];  // 2 x 16KB  [d][t], XOR-swizzled
  __shared__ short p_s[4][16 * 64];   // 8KB, per-wave [q][t]
  const int tid = threadIdx.x;
  const int wave = tid >> 6, lane = tid & 63;
  const int g = lane >> 4, l15 = lane & 15;
  const int bid = blockIdx.x;
  const int h = bid & 15;
  const int u = bid >> 4;
  const int qt = (u < 16) ? (2 * u) : (31 - 2 * (u - 16));
  const int q0 = qt * 64;
  const int ntiles = qt + 1;

  // staging geometry (per wave, 4 gload16 each for K and V):
  // K: LDS linear byte p = wave*4096 + i*1024 + lane*16 ; row=p>>8, chunk=p>>4&15
  //    swizzle flips chunk bits 0..2 by (row&7) -> source chunk = chunk^(row&7)
  const int krow_b = wave * 16 + (lane >> 4);           // +i*4
  const int vrow_b = wave * 32 + (lane >> 3);           // +i*8
#define STAGE_TILE(B, T0)                                                     \
  {                                                                           \
    _Pragma("unroll") for (int i = 0; i < 4; ++i) {                           \
      int rk = krow_b + i * 4;                                                \
      int ck = (lane & 15) ^ (rk & 7);                                        \
      gload16(kr + (size_t)((T0) + rk) * HID + h * HD + ck * 8,               \
              &k_s[B][0] + wave * 2048 + i * 512);                            \
      int rv = vrow_b + i * 8;                                                \
      int cv = (lane & 7) ^ (rv & 7);                                         \
      gload16(vT + (size_t)(h * HD + rv) * S_LEN + (T0) + cv * 8,             \
              &v_s[B][0] + wave * 2048 + i * 512);                            \
    }                                                                         \
  }

  bf16x8 qf[4];
#pragma unroll
  for (int ks = 0; ks < 4; ++ks) {
    int row = q0 + wave * 16 + l15;
    qf[ks] = *reinterpret_cast<const bf16x8*>(qr + (size_t)row * HID + h * HD +
                                              ks * 32 + g * 8);
  }

  STAGE_TILE(0, 0);
  __syncthreads();

  f32x4 o[8] = {};
  float m_run[4], l_run[4];
#pragma unroll
  for (int r = 0; r < 4; ++r) {
    m_run[r] = -3.0e38f;
    l_run[r] = 0.0f;
  }

  for (int kt = 0; kt < ntiles; ++kt) {
    const int cur = kt & 1;
    if (kt + 1 < ntiles) STAGE_TILE(cur ^ 1, (kt + 1) * 64);  // async prefetch

    // QK^T: 4 t-frags x 4 k-steps
    f32x4 sfr[4] = {};
    __builtin_amdgcn_s_setprio(1);
#pragma unroll
    for (int n = 0; n < 4; ++n) {
#pragma unroll
      for (int ks = 0; ks < 4; ++ks) {
        int rr = n * 16 + l15;
        int off = (rr * 256 + (ks * 32 + g * 8) * 2) ^ ((rr & 7) << 4);
        bf16x8 b =
            *reinterpret_cast<bf16x8*>(reinterpret_cast<char*>(k_s[cur]) + off);
        sfr[n] = __builtin_amdgcn_mfma_f32_16x16x32_bf16(qf[ks], b, sfr[n], 0,
                                                         0, 0);
      }
    }
    __builtin_amdgcn_s_setprio(0);

    const bool diag = (kt == qt);  // wave-uniform
#pragma unroll
    for (int r = 0; r < 4; ++r) {
      const int srow = q0 + wave * 16 + g * 4 + r;
      float mx = m_run[r];
#pragma unroll
      for (int n = 0; n < 4; ++n) {
        float val = sfr[n][r] * SCALE_QK;
        if (diag) {
          int t = kt * 64 + n * 16 + l15;
          val = (t <= srow) ? val : -3.0e38f;
        }
        sfr[n][r] = val;
        mx = fmaxf(mx, val);
      }
      mx = fmaxf(mx, __shfl_xor(mx, 1));
      mx = fmaxf(mx, __shfl_xor(mx, 2));
      mx = fmaxf(mx, __shfl_xor(mx, 4));
      mx = fmaxf(mx, __shfl_xor(mx, 8));
      float sum = 0.0f;
#pragma unroll
      for (int n = 0; n < 4; ++n) {
        float p = __expf(sfr[n][r] - mx);
        sfr[n][r] = p;
        sum += p;
      }
      sum += __shfl_xor(sum, 1);
      sum += __shfl_xor(sum, 2);
      sum += __shfl_xor(sum, 4);
      sum += __shfl_xor(sum, 8);
      float f = __expf(m_run[r] - mx);
      l_run[r] = l_run[r] * f + sum;
      m_run[r] = mx;
#pragma unroll
      for (int n = 0; n < 8; ++n) o[n][r] *= f;
    }

    // P -> bf16 -> wave-private swizzled LDS (16 x 64)
    char* pw = reinterpret_cast<char*>(p_s[wave]);
#pragma unroll
    for (int n = 0; n < 4; ++n)
#pragma unroll
      for (int r = 0; r < 4; ++r) {
        int rl = g * 4 + r;
        int off = (rl * 128 + (n * 16 + l15) * 2) ^ ((rl & 7) << 4);
        *reinterpret_cast<short*>(pw + off) = f2bf(sfr[n][r]);
      }

    // PV: 2 k-steps over t, 8 d-frags
    __builtin_amdgcn_s_setprio(1);
#pragma unroll
    for (int ks = 0; ks < 2; ++ks) {
      int offp = (l15 * 128 + (ks * 32 + g * 8) * 2) ^ ((l15 & 7) << 4);
      bf16x8 pa = *reinterpret_cast<bf16x8*>(pw + offp);
#pragma unroll
      for (int n = 0; n < 8; ++n) {
        int rr = n * 16 + l15;
        int off = (rr * 128 + (ks * 32 + g * 8) * 2) ^ ((rr & 7) << 4);
        bf16x8 vb =
            *reinterpret_cast<bf16x8*>(reinterpret_cast<char*>(v_s[cur]) + off);
        o[n] = __builtin_amdgcn_mfma_f32_16x16x32_bf16(pa, vb, o[n], 0, 0, 0);
      }
    }
    __builtin_amdgcn_s_setprio(0);

    __syncthreads();  // drains prefetch vmcnt + protects buffer reuse
  }
#undef STAGE_TILE

  // ---------------- epilogue: mem path + gate combine ----------------
  short* mt_s = &k_s[0][0];  // 32KB spans both k bufs (dead now)
#pragma unroll
  for (int i = 0; i < 8; ++i) {
    int c = tid + 256 * i;
    int r = c >> 4, kc = c & 15;
    int4 d = *reinterpret_cast<const int4*>(MT + (size_t)h * 16384 + r * 128 +
                                            kc * 8);
    *reinterpret_cast<int4*>(reinterpret_cast<char*>(mt_s) +
                             ((r * 256 + kc * 16) ^ ((r & 7) << 4))) = d;
  }
  __syncthreads();

  bf16x8 af[4];
#pragma unroll
  for (int ks = 0; ks < 4; ++ks) {
    int row = q0 + wave * 16 + l15;
    af[ks] = *reinterpret_cast<const bf16x8*>(sq + (size_t)row * HID + h * HD +
                                              ks * 32 + g * 8);
  }
  f32x4 acc2[8] = {};
#pragma unroll
  for (int ks = 0; ks < 4; ++ks) {
#pragma unroll
    for (int n = 0; n < 8; ++n) {
      int rr = n * 16 + l15;
      int off = (rr * 256 + (ks * 32 + g * 8) * 2) ^ ((rr & 7) << 4);
      bf16x8 b =
          *reinterpret_cast<bf16x8*>(reinterpret_cast<char*>(mt_s) + off);
      acc2[n] = __builtin_amdgcn_mfma_f32_16x16x32_bf16(af[ks], b, acc2[n], 0,
                                                        0, 0);
    }
  }

  float den[4];
#pragma unroll
  for (int r = 0; r < 4; ++r) {
    int row = q0 + wave * 16 + g * 4 + r;
    bf16x8 sv =
        *reinterpret_cast<const bf16x8*>(sq + (size_t)row * HID + h * HD +
                                         l15 * 8);
    float part = 0.0f;
#pragma unroll
    for (int j = 0; j < 8; ++j) part += bf2f(sv[j]) * z[h * HD + l15 * 8 + j];
    part += __shfl_xor(part, 1);
    part += __shfl_xor(part, 2);
    part += __shfl_xor(part, 4);
    part += __shfl_xor(part, 8);
    den[r] = part + 1e-8f;
  }

  float gv = 1.0f / (1.0f + __expf(-beta[0]));
#pragma unroll
  for (int n = 0; n < 8; ++n)
#pragma unroll
    for (int r = 0; r < 4; ++r) {
      int row = q0 + wave * 16 + g * 4 + r;
      int col = n * 16 + l15;
      float mem = acc2[n][r] / den[r];
      float at = o[n][r] / l_run[r];
      comb[(size_t)row * HID + h * HD + col] = f2bf(gv * mem + (1.0f - gv) * at);
    }
}

// --------------------------- M_new (split-K) --------------------------------
__global__ __launch_bounds__(256) void mnew_part_kernel(
    const short* __restrict__ skT, const short* __restrict__ vT,
    float* __restrict__ part) {
  const int sp = blockIdx.x;  // 0..7
  const int h = blockIdx.y;
  const int tid = threadIdx.x;
  const int wave = tid >> 6, lane = tid & 63;
  const int g = lane >> 4, l15 = lane & 15;
  f32x4 acc[2][8] = {};
  for (int ks = sp * 8; ks < sp * 8 + 8; ++ks) {
    bf16x8 a[2];
#pragma unroll
    for (int m = 0; m < 2; ++m) {
      int dd = wave * 32 + m * 16 + l15;
      a[m] = *reinterpret_cast<const bf16x8*>(skT + (size_t)(h * HD + dd) * S_LEN +
                                              ks * 32 + g * 8);
    }
#pragma unroll
    for (int n = 0; n < 8; ++n) {
      int e = n * 16 + l15;
      bf16x8 b = *reinterpret_cast<const bf16x8*>(
          vT + (size_t)(h * HD + e) * S_LEN + ks * 32 + g * 8);
#pragma unroll
      for (int m = 0; m < 2; ++m)
        acc[m][n] =
            __builtin_amdgcn_mfma_f32_16x16x32_bf16(a[m], b, acc[m][n], 0, 0, 0);
    }
  }
#pragma unroll
  for (int m = 0; m < 2; ++m)
#pragma unroll
    for (int n = 0; n < 8; ++n)
#pragma unroll
      for (int r = 0; r < 4; ++r) {
        int dd = wave * 32 + m * 16 + g * 4 + r;
        int e = n * 16 + l15;
        part[(size_t)(sp * 16 + h) * 16384 + (size_t)dd * 128 + e] =
            acc[m][n][r];
      }
}

__global__ __launch_bounds__(256) void mnew_reduce_kernel(
    const float* __restrict__ part, const float* __restrict__ Mold,
    float* __restrict__ Mout) {
  int idx = blockIdx.x * 256 + threadIdx.x;
  int j4 = idx * 4;
  int h = j4 >> 14;
  int rem = j4 & 16383;
  float4 a = *reinterpret_cast<const float4*>(Mold + j4);
#pragma unroll
  for (int s = 0; s < 8; ++s) {
    float4 p = *reinterpret_cast<const float4*>(
        part + ((size_t)(s * 16 + h) << 14) + rem);
    a.x += p.x;
    a.y += p.y;
    a.z += p.z;
    a.w += p.w;
  }
  *reinterpret_cast<float4*>(Mout + j4) = a;
}

// --------------------------- z_new -----------------------------------------
__global__ __launch_bounds__(256) void znew_kernel(const short* __restrict__ skT,
                                                   const float* __restrict__ z,
                                                   float* __restrict__ out) {
  int row = blockIdx.x;
  int tid = threadIdx.x;
  bf16x8 vv = *reinterpret_cast<const bf16x8*>(skT + (size_t)row * S_LEN + tid * 8);
  float s = 0.0f;
#pragma unroll
  for (int j = 0; j < 8; ++j) s += bf2f(vv[j]);
#pragma unroll
  for (int off = 1; off < 64; off <<= 1) s += __shfl_xor(s, off);
  __shared__ float wsum[4];
  if ((tid & 63) == 0) wsum[tid >> 6] = s;
  __syncthreads();
  if (tid == 0) out[row] = z[row] + wsum[0] + wsum[1] + wsum[2] + wsum[3];
}

// ---------------------------------------------------------------------------
extern "C" void kernel_launch(void* const* d_in, const int* in_sizes, int n_in,
                              void* d_out, int out_size, void* d_ws,
                              size_t ws_size, hipStream_t stream) {
  const float* hs = (const float*)d_in[0];
  const int* pos = (const int*)d_in[2];
  const float* Wq = (const float*)d_in[3];
  const float* bq = (const float*)d_in[4];
  const float* Wk = (const float*)d_in[5];
  const float* bk = (const float*)d_in[6];
  const float* Wo = (const float*)d_in[7];
  const float* beta = (const float*)d_in[8];
  const float* Mm = (const float*)d_in[9];
  const float* z = (const float*)d_in[10];
  float* out = (float*)d_out;

  char* ws = (char*)d_ws;
  const size_t MB = 1u << 20;
  float* q_f32 = (float*)(ws + 0);         // 16MB ; -> mnew partials later
  float* k_f32 = (float*)(ws + 16 * MB);   // 16MB ; -> comb after rope
  short* hs_b = (short*)(ws + 32 * MB);    // 8MB  ; -> sk after fused GEMM
  short* WqkT = (short*)(ws + 40 * MB);    // 16MB ; -> v/skT after fused GEMM
  short* WoT = (short*)(ws + 56 * MB);     // 8MB
  short* qr = (short*)(ws + 64 * MB);      // 8MB
  short* kr = (short*)(ws + 72 * MB);      // 8MB
  short* sq = (short*)(ws + 80 * MB);      // 8MB
  short* vT = (short*)(ws + 88 * MB);      // 8MB
  short* MT = (short*)(ws + 96 * MB);      // 512KB
  float* cost = (float*)(ws + 96 * MB + 512 * 1024);  // 512KB
  float* sint = (float*)(ws + 97 * MB);               // 512KB
  short* comb = (short*)k_f32;
  short* sk = hs_b;
  short* v = WqkT;
  short* skT = WqkT + 4 * 1024 * 1024;
  float* mpart = q_f32;  // 8MB partials (q_f32 dead after rope)

  f32_to_bf16_kernel<<<2048, 256, 0, stream>>>(hs, hs_b);
  transpose_f2b_kernel<<<dim3(64, 64, 1), 256, 0, stream>>>(Wq, WqkT, 2048, 2048);
  transpose_f2b_kernel<<<dim3(64, 64, 1), 256, 0, stream>>>(
      Wk, WqkT + 4 * 1024 * 1024, 2048, 2048);
  transpose_f2b_kernel<<<dim3(64, 64, 1), 256, 0, stream>>>(Wo, WoT, 2048, 2048);
  transpose_f2b_kernel<<<dim3(4, 4, 16), 256, 0, stream>>>(Mm, MT, 128, 128);
  tables_kernel<<<512, 256, 0, stream>>>(pos, cost, sint);

  gemm_bt_dual_kernel<<<dim3(16, 32), 256, 0, stream>>>(hs_b, WqkT, bq, bk,
                                                        q_f32, k_f32);
  rope_kernel<<<2048, 256, 0, stream>>>(q_f32, k_f32, cost, sint, qr, kr, sq, sk,
                                        v);
  transpose_b2b_kernel<<<dim3(64, 64, 1), 256, 0, stream>>>(v, vT, 2048, 2048);
  transpose_b2b_kernel<<<dim3(64, 64, 1), 256, 0, stream>>>(sk, skT, 2048, 2048);

  attn_kernel<<<512, 256, 0, stream>>>(qr, kr, vT, sq, MT, z, beta, comb);
  gemm_bt_dual_kernel<<<dim3(16, 16), 256, 0, stream>>>(comb, WoT, nullptr,
                                                        nullptr, out, out);
  mnew_part_kernel<<<dim3(8, 16), 256, 0, stream>>>(skT, vT, mpart);
  mnew_reduce_kernel<<<256, 256, 0, stream>>>(mpart, Mm, out + 4194304);
  znew_kernel<<<2048, 256, 0, stream>>>(skT, z, out + 4194304 + 16 * 128 * 128);
}

// Round 7
// 356.823 us; speedup vs baseline: 1.6183x; 1.0149x over previous
//
#include <hip/hip_runtime.h>
#include <hip/hip_bf16.h>

// ---------------------------------------------------------------------------
// InfiniAttention on MI355X — round 7.
// R6: attn fixed (82us, WRITE_SIZE 86->8MB). Remaining ~280us = m97-structure
// GEMMs with per-tile exposed load latency (stage->drain->compute).
// R7: GEMMs -> double-buffered prefetch-first single-barrier (T3 min 2-phase);
//     rope/elu fused into qk-GEMM epilogue (head-local d^64 partner via LDS).
// ---------------------------------------------------------------------------

#define S_LEN 2048
#define HID 2048
#define NH 16
#define HD 128
#define SCALE_QK 0.088388347648318447f

typedef __attribute__((ext_vector_type(8))) short bf16x8;
typedef __attribute__((ext_vector_type(4))) float f32x4;

__device__ __forceinline__ short f2bf(float f) {
  __hip_bfloat16 h = __float2bfloat16(f);
  return __builtin_bit_cast(short, h);
}
__device__ __forceinline__ float bf2f(short s) {
  unsigned int u = ((unsigned int)(unsigned short)s) << 16;
  return __builtin_bit_cast(float, u);
}
__device__ __forceinline__ void gload16(const void* g, void* l) {
  __builtin_amdgcn_global_load_lds(
      (const __attribute__((address_space(1))) void*)g,
      (__attribute__((address_space(3))) void*)l, 16, 0, 0);
}

// --------------------------- elementwise convert ---------------------------
__global__ __launch_bounds__(256) void f32_to_bf16_kernel(
    const float* __restrict__ in, short* __restrict__ out) {
  size_t i = (size_t)(blockIdx.x * 256 + threadIdx.x) * 8;
  float4 a = *reinterpret_cast<const float4*>(in + i);
  float4 b = *reinterpret_cast<const float4*>(in + i + 4);
  alignas(16) short t[8] = {f2bf(a.x), f2bf(a.y), f2bf(a.z), f2bf(a.w),
                            f2bf(b.x), f2bf(b.y), f2bf(b.z), f2bf(b.w)};
  *reinterpret_cast<int4*>(out + i) = *reinterpret_cast<int4*>(t);
}

// --------------------------- transposes ------------------------------------
__global__ __launch_bounds__(256) void transpose_f2b_kernel(
    const float* __restrict__ in, short* __restrict__ out, int R, int C) {
  __shared__ float t[32][33];
  size_t bo = (size_t)blockIdx.z * R * C;
  int r0 = blockIdx.y * 32, c0 = blockIdx.x * 32;
  int tx = threadIdx.x & 31, ty = threadIdx.x >> 5;
#pragma unroll
  for (int i = 0; i < 4; ++i)
    t[ty + i * 8][tx] = in[bo + (size_t)(r0 + ty + i * 8) * C + c0 + tx];
  __syncthreads();
#pragma unroll
  for (int i = 0; i < 4; ++i)
    out[bo + (size_t)(c0 + ty + i * 8) * R + r0 + tx] = f2bf(t[tx][ty + i * 8]);
}

__global__ __launch_bounds__(256) void transpose_b2b_kernel(
    const short* __restrict__ in, short* __restrict__ out, int R, int C) {
  __shared__ short t[32][33];
  int r0 = blockIdx.y * 32, c0 = blockIdx.x * 32;
  int tx = threadIdx.x & 31, ty = threadIdx.x >> 5;
#pragma unroll
  for (int i = 0; i < 4; ++i)
    t[ty + i * 8][tx] = in[(size_t)(r0 + ty + i * 8) * C + c0 + tx];
  __syncthreads();
#pragma unroll
  for (int i = 0; i < 4; ++i)
    out[(size_t)(c0 + ty + i * 8) * R + r0 + tx] = t[tx][ty + i * 8];
}

// --------------------------- rope tables -----------------------------------
__global__ __launch_bounds__(256) void tables_kernel(
    const int* __restrict__ pos_ids, float* __restrict__ cost,
    float* __restrict__ sint) {
  int idx = blockIdx.x * 256 + threadIdx.x;
  int s = idx >> 6, j = idx & 63;
  float pos = (float)pos_ids[s];
  float inv = powf(10000.0f, -((float)j) / 64.0f);
  float a = pos * inv;
  cost[idx] = cosf(a);
  sint[idx] = sinf(a);
}

// ------------- fused qk GEMM + rope/elu (dbuf, 1 barrier/tile) --------------
// [q|k] = hs @ [Wq|Wk]^T_stacked + bias, then rope+elu in epilogue.
// 128x128 tile, BK=64 double-buffered (64KB), 4 waves. colg0<2048 -> q path
// (writes qr,sq,v), else k path (writes kr,sk). Each block = one full head.
__global__ __launch_bounds__(256) void gemm_qk_rope_kernel(
    const short* __restrict__ A, const short* __restrict__ BT,
    const float* __restrict__ bq, const float* __restrict__ bk,
    const float* __restrict__ cost, const float* __restrict__ sint,
    short* __restrict__ qr, short* __restrict__ kr, short* __restrict__ sq,
    short* __restrict__ sk, short* __restrict__ v) {
  __shared__ __align__(16) char smem[67584];  // dbuf 64KB  /  qbuf 128x132 f32
  const int K = 2048;
  const int tid = threadIdx.x;
  const int wave = tid >> 6, lane = tid & 63;
  const int g = lane >> 4, l15 = lane & 15;
  const int wm = (wave >> 1) * 64, wn = (wave & 1) * 64;
  const int row0 = blockIdx.x * 128;
  const int colg0 = blockIdx.y * 128;

  const int ld_r = wave * 32 + (lane >> 3);
  const int ld_c = (lane & 7) * 8;
  const short* Ag = A + (size_t)(row0 + ld_r) * K + ld_c;
  const short* Bg = BT + (size_t)(colg0 + ld_r) * K + ld_c;

#define GSTAGE(BUF, KT)                                                       \
  {                                                                           \
    _Pragma("unroll") for (int i = 0; i < 4; ++i) {                           \
      gload16(Ag + (size_t)(KT) * 64 + (size_t)i * 8 * 2048,                  \
              smem + (BUF) * 32768 + wave * 4096 + i * 1024);                 \
      gload16(Bg + (size_t)(KT) * 64 + (size_t)i * 8 * 2048,                  \
              smem + (BUF) * 32768 + 16384 + wave * 4096 + i * 1024);         \
    }                                                                         \
  }

  f32x4 acc[4][4] = {};
  GSTAGE(0, 0);
  __syncthreads();
  for (int kt = 0; kt < 32; ++kt) {
    const int cur = kt & 1;
    if (kt + 1 < 32) GSTAGE(cur ^ 1, kt + 1);  // prefetch first (hidden)
#pragma unroll
    for (int ks = 0; ks < 2; ++ks) {
      bf16x8 a[4], b[4];
#pragma unroll
      for (int m = 0; m < 4; ++m)
        a[m] = *reinterpret_cast<bf16x8*>(smem + cur * 32768 +
                                          (wm + m * 16 + l15) * 128 +
                                          (ks * 32 + g * 8) * 2);
#pragma unroll
      for (int n = 0; n < 4; ++n)
        b[n] = *reinterpret_cast<bf16x8*>(smem + cur * 32768 + 16384 +
                                          (wn + n * 16 + l15) * 128 +
                                          (ks * 32 + g * 8) * 2);
#pragma unroll
      for (int m = 0; m < 4; ++m)
#pragma unroll
        for (int n = 0; n < 4; ++n)
          acc[m][n] = __builtin_amdgcn_mfma_f32_16x16x32_bf16(a[m], b[n],
                                                              acc[m][n], 0, 0, 0);
    }
    __syncthreads();  // drains prefetch; protects buffer reuse
  }
#undef GSTAGE

  // ---- epilogue: stage f32 result in LDS, apply rope/elu, write bf16 ----
  const bool qpath = (colg0 < 2048);
  const int col0 = qpath ? colg0 : colg0 - 2048;
  const float* bias = qpath ? bq : bk;
  float* qb = reinterpret_cast<float*>(smem);
#pragma unroll
  for (int m = 0; m < 4; ++m)
#pragma unroll
    for (int n = 0; n < 4; ++n) {
      int rl = wm + m * 16 + g * 4;
      int cl = wn + n * 16 + l15;
      float bv = bias[col0 + cl];
#pragma unroll
      for (int r = 0; r < 4; ++r) qb[(rl + r) * 132 + cl] = acc[m][n][r] + bv;
    }
  __syncthreads();

  const int rl = tid >> 1;               // 0..127
  const int c0 = (tid & 1) * 64;         // 0 or 64
  const int rowg = row0 + rl;
  const float sgn = (c0 == 0) ? -1.0f : 1.0f;
  const size_t obase = (size_t)rowg * HID + col0 + c0;
#pragma unroll
  for (int j0 = 0; j0 < 64; j0 += 8) {
    alignas(16) short o1[8], o2[8], o3[8];
#pragma unroll
    for (int jj = 0; jj < 8; ++jj) {
      int j = j0 + jj;
      float self = qb[rl * 132 + c0 + j];
      float part = qb[rl * 132 + (c0 ^ 64) + j];
      float cs = cost[rowg * 64 + j];
      float sn = sint[rowg * 64 + j];
      float rv = self * cs + sgn * part * sn;
      o1[jj] = f2bf(rv);
      o2[jj] = f2bf(rv > 0.0f ? rv + 1.0f : __expf(rv));
      o3[jj] = f2bf(self);
    }
    if (qpath) {
      *reinterpret_cast<int4*>(qr + obase + j0) = *reinterpret_cast<int4*>(o1);
      *reinterpret_cast<int4*>(sq + obase + j0) = *reinterpret_cast<int4*>(o2);
      *reinterpret_cast<int4*>(v + obase + j0) = *reinterpret_cast<int4*>(o3);
    } else {
      *reinterpret_cast<int4*>(kr + obase + j0) = *reinterpret_cast<int4*>(o1);
      *reinterpret_cast<int4*>(sk + obase + j0) = *reinterpret_cast<int4*>(o2);
    }
  }
}

// --------------- Wo GEMM (dbuf, 1 barrier/tile, f32 out) --------------------
__global__ __launch_bounds__(256) void gemm_wo_kernel(
    const short* __restrict__ A, const short* __restrict__ BT,
    float* __restrict__ C) {
  __shared__ __align__(16) char smem[65536];
  const int K = 2048;
  const int tid = threadIdx.x;
  const int wave = tid >> 6, lane = tid & 63;
  const int g = lane >> 4, l15 = lane & 15;
  const int wm = (wave >> 1) * 64, wn = (wave & 1) * 64;
  const int row0 = blockIdx.x * 128;
  const int col0 = blockIdx.y * 128;

  const int ld_r = wave * 32 + (lane >> 3);
  const int ld_c = (lane & 7) * 8;
  const short* Ag = A + (size_t)(row0 + ld_r) * K + ld_c;
  const short* Bg = BT + (size_t)(col0 + ld_r) * K + ld_c;

#define GSTAGE(BUF, KT)                                                       \
  {                                                                           \
    _Pragma("unroll") for (int i = 0; i < 4; ++i) {                           \
      gload16(Ag + (size_t)(KT) * 64 + (size_t)i * 8 * 2048,                  \
              smem + (BUF) * 32768 + wave * 4096 + i * 1024);                 \
      gload16(Bg + (size_t)(KT) * 64 + (size_t)i * 8 * 2048,                  \
              smem + (BUF) * 32768 + 16384 + wave * 4096 + i * 1024);         \
    }                                                                         \
  }

  f32x4 acc[4][4] = {};
  GSTAGE(0, 0);
  __syncthreads();
  for (int kt = 0; kt < 32; ++kt) {
    const int cur = kt & 1;
    if (kt + 1 < 32) GSTAGE(cur ^ 1, kt + 1);
#pragma unroll
    for (int ks = 0; ks < 2; ++ks) {
      bf16x8 a[4], b[4];
#pragma unroll
      for (int m = 0; m < 4; ++m)
        a[m] = *reinterpret_cast<bf16x8*>(smem + cur * 32768 +
                                          (wm + m * 16 + l15) * 128 +
                                          (ks * 32 + g * 8) * 2);
#pragma unroll
      for (int n = 0; n < 4; ++n)
        b[n] = *reinterpret_cast<bf16x8*>(smem + cur * 32768 + 16384 +
                                          (wn + n * 16 + l15) * 128 +
                                          (ks * 32 + g * 8) * 2);
#pragma unroll
      for (int m = 0; m < 4; ++m)
#pragma unroll
        for (int n = 0; n < 4; ++n)
          acc[m][n] = __builtin_amdgcn_mfma_f32_16x16x32_bf16(a[m], b[n],
                                                              acc[m][n], 0, 0, 0);
    }
    __syncthreads();
  }
#undef GSTAGE

#pragma unroll
  for (int m = 0; m < 4; ++m)
#pragma unroll
    for (int n = 0; n < 4; ++n) {
      int row = row0 + wm + m * 16 + g * 4;
      int col = col0 + wn + n * 16 + l15;
#pragma unroll
      for (int r = 0; r < 4; ++r)
        C[(size_t)(row + r) * 2048 + col] = acc[m][n][r];
    }
}

// --------------------------- flash attention + mem combine ------------------
// (unchanged from R6: gload_lds dbuf, 1 barrier/tile, setprio, fused combine)
__global__ __launch_bounds__(256) void attn_kernel(
    const short* __restrict__ qr, const short* __restrict__ kr,
    const short* __restrict__ vT, const short* __restrict__ sq,
    const short* __restrict__ MT, const float* __restrict__ z,
    const float* __restrict__ beta, short* __restrict__ comb) {
  __shared__ short k_s[2][64 * 128];
  __shared__ short v_s[2][128 * 64];
  __shared__ short p_s[4][16 * 64];
  const int tid = threadIdx.x;
  const int wave = tid >> 6, lane = tid & 63;
  const int g = lane >> 4, l15 = lane & 15;
  const int bid = blockIdx.x;
  const int h = bid & 15;
  const int u = bid >> 4;
  const int qt = (u < 16) ? (2 * u) : (31 - 2 * (u - 16));
  const int q0 = qt * 64;
  const int ntiles = qt + 1;

  const int krow_b = wave * 16 + (lane >> 4);
  const int vrow_b = wave * 32 + (lane >> 3);
#define STAGE_TILE(B, T0)                                                     \
  {                                                                           \
    _Pragma("unroll") for (int i = 0; i < 4; ++i) {                           \
      int rk = krow_b + i * 4;                                                \
      int ck = (lane & 15) ^ (rk & 7);                                        \
      gload16(kr + (size_t)((T0) + rk) * HID + h * HD + ck * 8,               \
              &k_s[B][0] + wave * 2048 + i * 512);                            \
      int rv = vrow_b + i * 8;                                                \
      int cv = (lane & 7) ^ (rv & 7);                                         \
      gload16(vT + (size_t)(h * HD + rv) * S_LEN + (T0) + cv * 8,             \
              &v_s[B][0] + wave * 2048 + i * 512);                            \
    }                                                                         \
  }

  bf16x8 qf[4];
#pragma unroll
  for (int ks = 0; ks < 4; ++ks) {
    int row = q0 + wave * 16 + l15;
    qf[ks] = *reinterpret_cast<const bf16x8*>(qr + (size_t)row * HID + h * HD +
                                              ks * 32 + g * 8);
  }

  STAGE_TILE(0, 0);
  __syncthreads();

  f32x4 o[8] = {};
  float m_run[4], l_run[4];
#pragma unroll
  for (int r = 0; r < 4; ++r) {
    m_run[r] = -3.0e38f;
    l_run[r] = 0.0f;
  }

  for (int kt = 0; kt < ntiles; ++kt) {
    const int cur = kt & 1;
    if (kt + 1 < ntiles) STAGE_TILE(cur ^ 1, (kt + 1) * 64);

    f32x4 sfr[4] = {};
    __builtin_amdgcn_s_setprio(1);
#pragma unroll
    for (int n = 0; n < 4; ++n) {
#pragma unroll
      for (int ks = 0; ks < 4; ++ks) {
        int rr = n * 16 + l15;
        int off = (rr * 256 + (ks * 32 + g * 8) * 2) ^ ((rr & 7) << 4);
        bf16x8 b =
            *reinterpret_cast<bf16x8*>(reinterpret_cast<char*>(k_s[cur]) + off);
        sfr[n] = __builtin_amdgcn_mfma_f32_16x16x32_bf16(qf[ks], b, sfr[n], 0,
                                                         0, 0);
      }
    }
    __builtin_amdgcn_s_setprio(0);

    const bool diag = (kt == qt);
#pragma unroll
    for (int r = 0; r < 4; ++r) {
      const int srow = q0 + wave * 16 + g * 4 + r;
      float mx = m_run[r];
#pragma unroll
      for (int n = 0; n < 4; ++n) {
        float val = sfr[n][r] * SCALE_QK;
        if (diag) {
          int t = kt * 64 + n * 16 + l15;
          val = (t <= srow) ? val : -3.0e38f;
        }
        sfr[n][r] = val;
        mx = fmaxf(mx, val);
      }
      mx = fmaxf(mx, __shfl_xor(mx, 1));
      mx = fmaxf(mx, __shfl_xor(mx, 2));
      mx = fmaxf(mx, __shfl_xor(mx, 4));
      mx = fmaxf(mx, __shfl_xor(mx, 8));
      float sum = 0.0f;
#pragma unroll
      for (int n = 0; n < 4; ++n) {
        float p = __expf(sfr[n][r] - mx);
        sfr[n][r] = p;
        sum += p;
      }
      sum += __shfl_xor(sum, 1);
      sum += __shfl_xor(sum, 2);
      sum += __shfl_xor(sum, 4);
      sum += __shfl_xor(sum, 8);
      float f = __expf(m_run[r] - mx);
      l_run[r] = l_run[r] * f + sum;
      m_run[r] = mx;
#pragma unroll
      for (int n = 0; n < 8; ++n) o[n][r] *= f;
    }

    char* pw = reinterpret_cast<char*>(p_s[wave]);
#pragma unroll
    for (int n = 0; n < 4; ++n)
#pragma unroll
      for (int r = 0; r < 4; ++r) {
        int rl = g * 4 + r;
        int off = (rl * 128 + (n * 16 + l15) * 2) ^ ((rl & 7) << 4);
        *reinterpret_cast<short*>(pw + off) = f2bf(sfr[n][r]);
      }

    __builtin_amdgcn_s_setprio(1);
#pragma unroll
    for (int ks = 0; ks < 2; ++ks) {
      int offp = (l15 * 128 + (ks * 32 + g * 8) * 2) ^ ((l15 & 7) << 4);
      bf16x8 pa = *reinterpret_cast<bf16x8*>(pw + offp);
#pragma unroll
      for (int n = 0; n < 8; ++n) {
        int rr = n * 16 + l15;
        int off = (rr * 128 + (ks * 32 + g * 8) * 2) ^ ((rr & 7) << 4);
        bf16x8 vb =
            *reinterpret_cast<bf16x8*>(reinterpret_cast<char*>(v_s[cur]) + off);
        o[n] = __builtin_amdgcn_mfma_f32_16x16x32_bf16(pa, vb, o[n], 0, 0, 0);
      }
    }
    __builtin_amdgcn_s_setprio(0);

    __syncthreads();
  }
#undef STAGE_TILE

  short* mt_s = &k_s[0][0];
#pragma unroll
  for (int i = 0; i < 8; ++i) {
    int c = tid + 256 * i;
    int r = c >> 4, kc = c & 15;
    int4 d = *reinterpret_cast<const int4*>(MT + (size_t)h * 16384 + r * 128 +
                                            kc * 8);
    *reinterpret_cast<int4*>(reinterpret_cast<char*>(mt_s) +
                             ((r * 256 + kc * 16) ^ ((r & 7) << 4))) = d;
  }
  __syncthreads();

  bf16x8 af[4];
#pragma unroll
  for (int ks = 0; ks < 4; ++ks) {
    int row = q0 + wave * 16 + l15;
    af[ks] = *reinterpret_cast<const bf16x8*>(sq + (size_t)row * HID + h * HD +
                                              ks * 32 + g * 8);
  }
  f32x4 acc2[8] = {};
#pragma unroll
  for (int ks = 0; ks < 4; ++ks) {
#pragma unroll
    for (int n = 0; n < 8; ++n) {
      int rr = n * 16 + l15;
      int off = (rr * 256 + (ks * 32 + g * 8) * 2) ^ ((rr & 7) << 4);
      bf16x8 b =
          *reinterpret_cast<bf16x8*>(reinterpret_cast<char*>(mt_s) + off);
      acc2[n] = __builtin_amdgcn_mfma_f32_16x16x32_bf16(af[ks], b, acc2[n], 0,
                                                        0, 0);
    }
  }

  float den[4];
#pragma unroll
  for (int r = 0; r < 4; ++r) {
    int row = q0 + wave * 16 + g * 4 + r;
    bf16x8 sv = *reinterpret_cast<const bf16x8*>(sq + (size_t)row * HID +
                                                 h * HD + l15 * 8);
    float part = 0.0f;
#pragma unroll
    for (int j = 0; j < 8; ++j) part += bf2f(sv[j]) * z[h * HD + l15 * 8 + j];
    part += __shfl_xor(part, 1);
    part += __shfl_xor(part, 2);
    part += __shfl_xor(part, 4);
    part += __shfl_xor(part, 8);
    den[r] = part + 1e-8f;
  }

  float gv = 1.0f / (1.0f + __expf(-beta[0]));
#pragma unroll
  for (int n = 0; n < 8; ++n)
#pragma unroll
    for (int r = 0; r < 4; ++r) {
      int row = q0 + wave * 16 + g * 4 + r;
      int col = n * 16 + l15;
      float mem = acc2[n][r] / den[r];
      float at = o[n][r] / l_run[r];
      comb[(size_t)row * HID + h * HD + col] = f2bf(gv * mem + (1.0f - gv) * at);
    }
}

// --------------------------- M_new (split-K) --------------------------------
__global__ __launch_bounds__(256) void mnew_part_kernel(
    const short* __restrict__ skT, const short* __restrict__ vT,
    float* __restrict__ part) {
  const int sp = blockIdx.x;
  const int h = blockIdx.y;
  const int tid = threadIdx.x;
  const int wave = tid >> 6, lane = tid & 63;
  const int g = lane >> 4, l15 = lane & 15;
  f32x4 acc[2][8] = {};
  for (int ks = sp * 8; ks < sp * 8 + 8; ++ks) {
    bf16x8 a[2];
#pragma unroll
    for (int m = 0; m < 2; ++m) {
      int dd = wave * 32 + m * 16 + l15;
      a[m] = *reinterpret_cast<const bf16x8*>(skT + (size_t)(h * HD + dd) * S_LEN +
                                              ks * 32 + g * 8);
    }
#pragma unroll
    for (int n = 0; n < 8; ++n) {
      int e = n * 16 + l15;
      bf16x8 b = *reinterpret_cast<const bf16x8*>(
          vT + (size_t)(h * HD + e) * S_LEN + ks * 32 + g * 8);
#pragma unroll
      for (int m = 0; m < 2; ++m)
        acc[m][n] =
            __builtin_amdgcn_mfma_f32_16x16x32_bf16(a[m], b, acc[m][n], 0, 0, 0);
    }
  }
#pragma unroll
  for (int m = 0; m < 2; ++m)
#pragma unroll
    for (int n = 0; n < 8; ++n)
#pragma unroll
      for (int r = 0; r < 4; ++r) {
        int dd = wave * 32 + m * 16 + g * 4 + r;
        int e = n * 16 + l15;
        part[(size_t)(sp * 16 + h) * 16384 + (size_t)dd * 128 + e] =
            acc[m][n][r];
      }
}

__global__ __launch_bounds__(256) void mnew_reduce_kernel(
    const float* __restrict__ part, const float* __restrict__ Mold,
    float* __restrict__ Mout) {
  int idx = blockIdx.x * 256 + threadIdx.x;
  int j4 = idx * 4;
  int h = j4 >> 14;
  int rem = j4 & 16383;
  float4 a = *reinterpret_cast<const float4*>(Mold + j4);
#pragma unroll
  for (int s = 0; s < 8; ++s) {
    float4 p = *reinterpret_cast<const float4*>(
        part + ((size_t)(s * 16 + h) << 14) + rem);
    a.x += p.x;
    a.y += p.y;
    a.z += p.z;
    a.w += p.w;
  }
  *reinterpret_cast<float4*>(Mout + j4) = a;
}

// --------------------------- z_new -----------------------------------------
__global__ __launch_bounds__(256) void znew_kernel(const short* __restrict__ skT,
                                                   const float* __restrict__ z,
                                                   float* __restrict__ out) {
  int row = blockIdx.x;
  int tid = threadIdx.x;
  bf16x8 vv = *reinterpret_cast<const bf16x8*>(skT + (size_t)row * S_LEN + tid * 8);
  float s = 0.0f;
#pragma unroll
  for (int j = 0; j < 8; ++j) s += bf2f(vv[j]);
#pragma unroll
  for (int off = 1; off < 64; off <<= 1) s += __shfl_xor(s, off);
  __shared__ float wsum[4];
  if ((tid & 63) == 0) wsum[tid >> 6] = s;
  __syncthreads();
  if (tid == 0) out[row] = z[row] + wsum[0] + wsum[1] + wsum[2] + wsum[3];
}

// ---------------------------------------------------------------------------
extern "C" void kernel_launch(void* const* d_in, const int* in_sizes, int n_in,
                              void* d_out, int out_size, void* d_ws,
                              size_t ws_size, hipStream_t stream) {
  const float* hs = (const float*)d_in[0];
  const int* pos = (const int*)d_in[2];
  const float* Wq = (const float*)d_in[3];
  const float* bq = (const float*)d_in[4];
  const float* Wk = (const float*)d_in[5];
  const float* bk = (const float*)d_in[6];
  const float* Wo = (const float*)d_in[7];
  const float* beta = (const float*)d_in[8];
  const float* Mm = (const float*)d_in[9];
  const float* z = (const float*)d_in[10];
  float* out = (float*)d_out;

  char* ws = (char*)d_ws;
  const size_t MB = 1u << 20;
  short* hs_b = (short*)(ws + 0);          // 8MB ; -> mpart after qk GEMM
  short* WqkT = (short*)(ws + 8 * MB);     // 16MB; -> skT/vT after qk GEMM
  short* WoT = (short*)(ws + 24 * MB);     // 8MB
  short* qr = (short*)(ws + 32 * MB);      // 8MB
  short* kr = (short*)(ws + 40 * MB);      // 8MB
  short* sq = (short*)(ws + 48 * MB);      // 8MB
  short* sk = (short*)(ws + 56 * MB);      // 8MB
  short* v = (short*)(ws + 64 * MB);       // 8MB
  short* comb = (short*)(ws + 72 * MB);    // 8MB
  short* MT = (short*)(ws + 80 * MB);      // 512KB
  float* cost = (float*)(ws + 80 * MB + 512 * 1024);  // 512KB
  float* sint = (float*)(ws + 81 * MB);               // 512KB
  // aliases (lifetime-checked):
  short* skT = WqkT;                       // WqkT dead after qk GEMM
  short* vT = WqkT + 4 * 1024 * 1024;
  float* mpart = (float*)hs_b;             // hs_b dead after qk GEMM

  f32_to_bf16_kernel<<<2048, 256, 0, stream>>>(hs, hs_b);
  transpose_f2b_kernel<<<dim3(64, 64, 1), 256, 0, stream>>>(Wq, WqkT, 2048, 2048);
  transpose_f2b_kernel<<<dim3(64, 64, 1), 256, 0, stream>>>(
      Wk, WqkT + 4 * 1024 * 1024, 2048, 2048);
  transpose_f2b_kernel<<<dim3(64, 64, 1), 256, 0, stream>>>(Wo, WoT, 2048, 2048);
  transpose_f2b_kernel<<<dim3(4, 4, 16), 256, 0, stream>>>(Mm, MT, 128, 128);
  tables_kernel<<<512, 256, 0, stream>>>(pos, cost, sint);

  gemm_qk_rope_kernel<<<dim3(16, 32), 256, 0, stream>>>(
      hs_b, WqkT, bq, bk, cost, sint, qr, kr, sq, sk, v);
  transpose_b2b_kernel<<<dim3(64, 64, 1), 256, 0, stream>>>(v, vT, 2048, 2048);
  transpose_b2b_kernel<<<dim3(64, 64, 1), 256, 0, stream>>>(sk, skT, 2048, 2048);

  attn_kernel<<<512, 256, 0, stream>>>(qr, kr, vT, sq, MT, z, beta, comb);
  gemm_wo_kernel<<<dim3(16, 16), 256, 0, stream>>>(comb, WoT, out);
  mnew_part_kernel<<<dim3(8, 16), 256, 0, stream>>>(skT, vT, mpart);
  mnew_reduce_kernel<<<256, 256, 0, stream>>>(mpart, Mm, out + 4194304);
  znew_kernel<<<2048, 256, 0, stream>>>(skT, z, out + 4194304 + 16 * 128 * 128);
}